// Round 1
// baseline (265.251 us; speedup 1.0000x reference)
//
#include <hip/hip_runtime.h>
#include <cstddef>

#define B_    16
#define SQ_   1024
#define SE_   1024
#define CIN_  256
#define DK_   64
#define H_    8
#define HD_   512
#define NROWS 16384
#define BN_EPS 1e-5f
#define NEG_SLOPE 0.01f

typedef __attribute__((ext_vector_type(8))) short bf16x8;
typedef __attribute__((ext_vector_type(4))) float f32x4;

__device__ __forceinline__ unsigned short f2bf(float f) {  // RNE
    unsigned int u = __float_as_uint(f);
    return (unsigned short)((u + 0x7FFFu + ((u >> 16) & 1u)) >> 16);
}

#if __has_builtin(__builtin_amdgcn_perm)
__device__ __forceinline__ unsigned int pack_trunc(float lo, float hi) {
    return __builtin_amdgcn_perm(__float_as_uint(hi), __float_as_uint(lo), 0x07060302u);
}
#else
__device__ __forceinline__ unsigned int pack_trunc(float lo, float hi) {
    return (__float_as_uint(lo) >> 16) | (__float_as_uint(hi) & 0xFFFF0000u);
}
#endif

#if __has_builtin(__builtin_amdgcn_exp2f)
#define EXP2F(x) __builtin_amdgcn_exp2f(x)
#else
#define EXP2F(x) exp2f(x)
#endif

__device__ __forceinline__ ushort4 pack4(f32x4 v) {
    ushort4 p;
    p.x = f2bf(v[0]); p.y = f2bf(v[1]);
    p.z = f2bf(v[2]); p.w = f2bf(v[3]);
    return p;
}

// ---------------------------------------------------------------------------
// Weight casts (one dispatch). Wq gets 0.125*log2(e) folded in.
// Blocks 0..1 also zero the BN stats accumulators.
// ---------------------------------------------------------------------------
__global__ __launch_bounds__(256) void wcast(const float* __restrict__ Wq,
                                             const float* __restrict__ Wk,
                                             const float* __restrict__ Wv,
                                             const float* __restrict__ Wp,
                                             unsigned short* __restrict__ dWq,
                                             unsigned short* __restrict__ dWkv,
                                             unsigned short* __restrict__ dWp,
                                             float* __restrict__ stats) {
    if (blockIdx.x < 2) stats[blockIdx.x * 256 + threadIdx.x] = 0.f;
    int i = blockIdx.x * 256 + threadIdx.x;
    int which = i >> 15, off = i & 32767;
    const float* s; unsigned short* d; float sc = 1.0f;
    if (which == 0)      { s = Wq; d = dWq; sc = 0.18033688011112042f; }
    else if (which == 1) { s = Wk; d = dWkv; }
    else if (which == 2) { s = Wv; d = dWkv + 131072; }
    else                 { s = Wp; d = dWp; }
    float4 v = *(const float4*)(s + (size_t)off * 4);
    ushort4 pk;
    pk.x = f2bf(v.x * sc); pk.y = f2bf(v.y * sc);
    pk.z = f2bf(v.z * sc); pk.w = f2bf(v.w * sc);
    *(ushort4*)(d + (size_t)off * 4) = pk;
}

// ---------------------------------------------------------------------------
// Fused Q+KV projection GEMM, 128x128 tile, BK=64, f32 A with cast fused
// into LDS staging (no qbf/xbf intermediate), register prefetch.
// grid (12,128): bx<4 Q, 4..7 K, 8..11 V.
// Q/K: transposed compute mfma(W,A); V: normal compute (vT layout).
// Epilogue: LDS-staged full-line coalesced stores (R12 pattern).
// ---------------------------------------------------------------------------
__global__ __launch_bounds__(256) void gemm_qkv6(const float* __restrict__ qsrc,
                                                 const float* __restrict__ xsrc,
                                                 const unsigned short* __restrict__ Wqb,
                                                 const unsigned short* __restrict__ Wkvb,
                                                 unsigned short* __restrict__ qh,
                                                 unsigned short* __restrict__ khb,
                                                 unsigned short* __restrict__ vTb) {
    __shared__ __align__(16) unsigned short smem[18432];    // 36 KB
    unsigned short* As = smem;                              // 128*72
    unsigned short* Ws = smem + 9216;                       // 128*72
    unsigned short* Cs = smem;                              // epilogue: 128*144

    const int tid = threadIdx.x;
    const int w = tid >> 6, l = tid & 63, lq = l >> 4, lr = l & 15;
    const int bx = blockIdx.x;
    const bool isQ = bx < 4;
    const bool isV = bx >= 8;
    const float* A = isQ ? qsrc : xsrc;
    const unsigned short* W = isQ ? Wqb : Wkvb;
    const int n0 = (isQ ? bx : bx - 4) * 128;
    const int m0 = blockIdx.y * 128;
    const int K = 256;

    const int srow = tid >> 1, soff = (tid & 1) * 32;   // 32 elems/thread

    f32x4 acc[2][8] = {};
    uint4 aR[8], wR[4];

    {
        const float* Ar = A + (size_t)(m0 + srow) * K + soff;
        #pragma unroll
        for (int c = 0; c < 8; ++c) aR[c] = *(const uint4*)(Ar + c * 4);
        const unsigned short* Wr = W + (size_t)(n0 + srow) * K + soff;
        #pragma unroll
        for (int c = 0; c < 4; ++c) wR[c] = *(const uint4*)(Wr + c * 8);
    }

    for (int k0 = 0; k0 < K; k0 += 64) {
        __syncthreads();
        #pragma unroll
        for (int c = 0; c < 4; ++c) {
            float4 u0 = *(float4*)&aR[2 * c];
            float4 u1 = *(float4*)&aR[2 * c + 1];
            uint4 pk;
            pk.x = pack_trunc(u0.x, u0.y);
            pk.y = pack_trunc(u0.z, u0.w);
            pk.z = pack_trunc(u1.x, u1.y);
            pk.w = pack_trunc(u1.z, u1.w);
            *(uint4*)&As[srow * 72 + soff + c * 8] = pk;
            *(uint4*)&Ws[srow * 72 + soff + c * 8] = wR[c];
        }
        if (k0 + 64 < K) {
            const float* Ar = A + (size_t)(m0 + srow) * K + k0 + 64 + soff;
            #pragma unroll
            for (int c = 0; c < 8; ++c) aR[c] = *(const uint4*)(Ar + c * 4);
            const unsigned short* Wr = W + (size_t)(n0 + srow) * K + k0 + 64 + soff;
            #pragma unroll
            for (int c = 0; c < 4; ++c) wR[c] = *(const uint4*)(Wr + c * 8);
        }
        __syncthreads();

        if (!isV) {   // transposed compute: D[n][m]
            #pragma unroll
            for (int ks = 0; ks < 2; ++ks) {
                bf16x8 a0 = *(bf16x8*)&As[(w * 32 + lr) * 72 + ks * 32 + lq * 8];
                bf16x8 a1 = *(bf16x8*)&As[(w * 32 + 16 + lr) * 72 + ks * 32 + lq * 8];
                #pragma unroll
                for (int j = 0; j < 8; ++j) {
                    bf16x8 bb = *(bf16x8*)&Ws[(j * 16 + lr) * 72 + ks * 32 + lq * 8];
                    acc[0][j] = __builtin_amdgcn_mfma_f32_16x16x32_bf16(bb, a0, acc[0][j], 0, 0, 0);
                    acc[1][j] = __builtin_amdgcn_mfma_f32_16x16x32_bf16(bb, a1, acc[1][j], 0, 0, 0);
                }
            }
        } else {      // normal compute: D[m][n]
            #pragma unroll
            for (int ks = 0; ks < 2; ++ks) {
                bf16x8 a0 = *(bf16x8*)&As[(w * 32 + lr) * 72 + ks * 32 + lq * 8];
                bf16x8 a1 = *(bf16x8*)&As[(w * 32 + 16 + lr) * 72 + ks * 32 + lq * 8];
                #pragma unroll
                for (int j = 0; j < 8; ++j) {
                    bf16x8 bb = *(bf16x8*)&Ws[(j * 16 + lr) * 72 + ks * 32 + lq * 8];
                    acc[0][j] = __builtin_amdgcn_mfma_f32_16x16x32_bf16(a0, bb, acc[0][j], 0, 0, 0);
                    acc[1][j] = __builtin_amdgcn_mfma_f32_16x16x32_bf16(a1, bb, acc[1][j], 0, 0, 0);
                }
            }
        }
    }

    // ---- Epilogue: LDS staging, then full-line coalesced stores ----
    __syncthreads();
    const int c16 = tid & 15;
    const int rb  = tid >> 4;
    if (!isV) {
        #pragma unroll
        for (int mf = 0; mf < 2; ++mf)
            #pragma unroll
            for (int j = 0; j < 8; ++j)
                *(ushort4*)&Cs[(w * 32 + mf * 16 + lr) * 144 + j * 16 + lq * 4] =
                    pack4(acc[mf][j]);
        __syncthreads();
        unsigned short* C = isQ ? qh : khb;
        #pragma unroll
        for (int it = 0; it < 8; ++it) {
            int r = it * 16 + rb;
            *(uint4*)(C + (size_t)(m0 + r) * 512 + n0 + c16 * 8) =
                *(const uint4*)(Cs + r * 144 + c16 * 8);
        }
    } else {
        #pragma unroll
        for (int mf = 0; mf < 2; ++mf)
            #pragma unroll
            for (int j = 0; j < 8; ++j)
                *(ushort4*)&Cs[(j * 16 + lr) * 144 + w * 32 + mf * 16 + lq * 4] =
                    pack4(acc[mf][j]);
        __syncthreads();
        const int bb = m0 >> 10, t0 = m0 & 1023;
        #pragma unroll
        for (int it = 0; it < 8; ++it) {
            int el = it * 16 + rb;
            int colv = n0 - 512 + el;
            int hh = colv >> 6, e = colv & 63;
            *(uint4*)(vTb + (size_t)((bb * 8 + hh) * 64 + e) * 1024 + t0 + c16 * 8) =
                *(const uint4*)(Cs + el * 144 + c16 * 8);
        }
    }
}

// ---------------------------------------------------------------------------
// MFMA flash attention v9: v8 + async K/V staging split (T14) + setprio
// around MFMA clusters (T5, attn-positive per m191).
// 256 q-rows/block, 64 q-rows/wave. LDS 54KB, 2 blocks/CU.
// K/V tile register-prefetch: issue next tile's global loads right after
// LDS writes; vmcnt wait lands at next iteration's LDS write, hiding the
// L2/L3 latency under QK^T+softmax+PV.
// ---------------------------------------------------------------------------
__global__ __launch_bounds__(256) void attn_mfma9(const unsigned short* __restrict__ qh,
                                                  const unsigned short* __restrict__ kh,
                                                  const unsigned short* __restrict__ vT,
                                                  unsigned short* __restrict__ o) {
    __shared__ __align__(16) unsigned short Ks[64 * 72];      // [key][d]   9.2 KB
    __shared__ __align__(16) unsigned short Vs[64 * 72];      // [e][t]     9.2 KB
    __shared__ __align__(16) unsigned short Ps[4][64 * 72];   // per-wave P 36.9 KB

    const int tid = threadIdx.x;
    const int w = tid >> 6, l = tid & 63, lq = l >> 4, lr = l & 15;
    const int q0 = blockIdx.x * 256, h = blockIdx.y, b = blockIdx.z;

    // Q fragments: lane lr holds row m = mm*16+lr, elems k = lq*8+j (+32)
    bf16x8 qf[4][2];
    #pragma unroll
    for (int mm = 0; mm < 4; ++mm) {
        const unsigned short* qr =
            qh + (size_t)(b * SQ_ + q0 + w * 64 + mm * 16 + lr) * HD_ + h * DK_;
        qf[mm][0] = *(const bf16x8*)(qr + lq * 8);
        qf[mm][1] = *(const bf16x8*)(qr + 32 + lq * 8);
    }

    const unsigned short* kb = kh + (size_t)(b * SE_) * HD_ + h * DK_;
    const unsigned short* vb = vT + (size_t)((b * 8 + h) * 64) * 1024;

    const int se = tid >> 3;        // 0..31
    const int sc = (tid & 7) * 8;

    float l_i[4] = {};              // per-lane partial row-sum; m = mm*16 + lr
    f32x4 oacc[4][4] = {};          // [mm][e-strip j]; D[e][m]
    unsigned short* Pw = Ps[w];

    // ---- prefetch K/V tile 0 into registers ----
    uint4 kR[2], vR[2];
    #pragma unroll
    for (int ps = 0; ps < 2; ++ps) {
        int rr = se + ps * 32;
        kR[ps] = *(const uint4*)(kb + (size_t)rr * HD_ + sc);
        vR[ps] = *(const uint4*)(vb + (size_t)rr * 1024 + sc);
    }

    for (int t0 = 0; t0 < SE_; t0 += 64) {
        __syncthreads();
        // write current tile (regs -> LDS); vmcnt wait auto-inserted here
        #pragma unroll
        for (int ps = 0; ps < 2; ++ps) {
            int rr = se + ps * 32;
            *(uint4*)&Ks[rr * 72 + sc] = kR[ps];
            *(uint4*)&Vs[rr * 72 + sc] = vR[ps];
        }
        // issue next tile's loads (no wait) -- latency hides under compute
        if (t0 + 64 < SE_) {
            #pragma unroll
            for (int ps = 0; ps < 2; ++ps) {
                int rr = se + ps * 32;
                kR[ps] = *(const uint4*)(kb + (size_t)(t0 + 64 + rr) * HD_ + sc);
                vR[ps] = *(const uint4*)(vb + (size_t)rr * 1024 + t0 + 64 + sc);
            }
        }
        __syncthreads();

        // S^T tiles: sT[tt][mm]; C row = t (lq*4+r), col = m (lr).
        // kf read once per (ks,tt), reused across 4 mm.
        f32x4 sT[4][4] = {};
        __builtin_amdgcn_s_setprio(1);
        #pragma unroll
        for (int ks = 0; ks < 2; ++ks)
            #pragma unroll
            for (int tt = 0; tt < 4; ++tt) {
                bf16x8 kf = *(bf16x8*)&Ks[(tt * 16 + lr) * 72 + ks * 32 + lq * 8];
                #pragma unroll
                for (int mm = 0; mm < 4; ++mm)
                    sT[tt][mm] = __builtin_amdgcn_mfma_f32_16x16x32_bf16(kf, qf[mm][ks], sT[tt][mm], 0, 0, 0);
            }
        __builtin_amdgcn_s_setprio(0);

        // exp2 + lane-local l accum + packed b64 P write (4 consecutive t)
        #pragma unroll
        for (int mm = 0; mm < 4; ++mm)
            #pragma unroll
            for (int tt = 0; tt < 4; ++tt) {
                float e0 = EXP2F(sT[tt][mm][0]);
                float e1 = EXP2F(sT[tt][mm][1]);
                float e2 = EXP2F(sT[tt][mm][2]);
                float e3 = EXP2F(sT[tt][mm][3]);
                l_i[mm] += (e0 + e1) + (e2 + e3);
                uint2 pk;
                pk.x = pack_trunc(e0, e1);
                pk.y = pack_trunc(e2, e3);
                *(uint2*)&Pw[(mm * 16 + lr) * 72 + tt * 16 + lq * 4] = pk;
            }
        asm volatile("s_waitcnt lgkmcnt(0)" ::: "memory");   // wave-local round trip

        // PV transposed: oacc[mm][j] = V_strip_j . P_mm^T -> D[e][m].
        // vf read once per (ks,j), reused across 4 mm.
        __builtin_amdgcn_s_setprio(1);
        #pragma unroll
        for (int ks = 0; ks < 2; ++ks) {
            bf16x8 pf[4];
            #pragma unroll
            for (int mm = 0; mm < 4; ++mm)
                pf[mm] = *(bf16x8*)&Pw[(mm * 16 + lr) * 72 + ks * 32 + lq * 8];
            #pragma unroll
            for (int j = 0; j < 4; ++j) {
                bf16x8 vf = *(bf16x8*)&Vs[(j * 16 + lr) * 72 + ks * 32 + lq * 8];
                #pragma unroll
                for (int mm = 0; mm < 4; ++mm)
                    oacc[mm][j] = __builtin_amdgcn_mfma_f32_16x16x32_bf16(vf, pf[mm], oacc[mm][j], 0, 0, 0);
            }
        }
        __builtin_amdgcn_s_setprio(0);
    }

    float inv[4];
    #pragma unroll
    for (int mm = 0; mm < 4; ++mm) {
        float t = l_i[mm];
        t += __shfl_xor(t, 16);
        t += __shfl_xor(t, 32);
        inv[mm] = 1.0f / t;
    }

    // o store: D row = e_local = lq*4+r (4 consecutive e), col = m = lr.
    #pragma unroll
    for (int mm = 0; mm < 4; ++mm)
        #pragma unroll
        for (int j = 0; j < 4; ++j) {
            f32x4 v = oacc[mm][j];
            v[0] *= inv[mm]; v[1] *= inv[mm]; v[2] *= inv[mm]; v[3] *= inv[mm];
            *(ushort4*)&o[(size_t)(b * SQ_ + q0 + w * 64 + mm * 16 + lr) * HD_ +
                          h * DK_ + j * 16 + lq * 4] = pack4(v);
        }
}

// ---------------------------------------------------------------------------
// Output projection: p = o @ Wp^T (bf16 in, f32 out) + fused BN partials.
// 128x64 tiles, K=512, register prefetch.
// ---------------------------------------------------------------------------
__global__ __launch_bounds__(256) void gemm_out(const unsigned short* __restrict__ A,
                                                const unsigned short* __restrict__ W,
                                                float* __restrict__ C,
                                                float* __restrict__ gsum,
                                                float* __restrict__ gsumsq) {
    __shared__ __align__(16) unsigned short As[128 * 72];
    __shared__ __align__(16) unsigned short Ws[64 * 72];
    const int tid = threadIdx.x;
    const int w = tid >> 6, l = tid & 63, lq = l >> 4, lr = l & 15;
    const int n0 = blockIdx.x * 64, m0 = blockIdx.y * 128;
    const int K = 512;

    const int arow = tid >> 1, aoff = (tid & 1) * 32;
    const int wrow = tid >> 2, woff = (tid & 3) * 16;

    f32x4 acc[2][4] = {};
    uint4 aR[4], wR[2];

    {
        const unsigned short* Ar = A + (size_t)(m0 + arow) * K + aoff;
        #pragma unroll
        for (int c = 0; c < 4; ++c) aR[c] = *(const uint4*)(Ar + c * 8);
        const unsigned short* Wr = W + (size_t)(n0 + wrow) * K + woff;
        #pragma unroll
        for (int c = 0; c < 2; ++c) wR[c] = *(const uint4*)(Wr + c * 8);
    }

    for (int k0 = 0; k0 < K; k0 += 64) {
        __syncthreads();
        #pragma unroll
        for (int c = 0; c < 4; ++c)
            *(uint4*)&As[arow * 72 + aoff + c * 8] = aR[c];
        #pragma unroll
        for (int c = 0; c < 2; ++c)
            *(uint4*)&Ws[wrow * 72 + woff + c * 8] = wR[c];

        if (k0 + 64 < K) {
            const unsigned short* Ar = A + (size_t)(m0 + arow) * K + k0 + 64 + aoff;
            #pragma unroll
            for (int c = 0; c < 4; ++c) aR[c] = *(const uint4*)(Ar + c * 8);
            const unsigned short* Wr = W + (size_t)(n0 + wrow) * K + k0 + 64 + woff;
            #pragma unroll
            for (int c = 0; c < 2; ++c) wR[c] = *(const uint4*)(Wr + c * 8);
        }
        __syncthreads();

        #pragma unroll
        for (int ks = 0; ks < 2; ++ks) {
            bf16x8 a0 = *(bf16x8*)&As[(w * 32 + lr) * 72 + ks * 32 + lq * 8];
            bf16x8 a1 = *(bf16x8*)&As[(w * 32 + 16 + lr) * 72 + ks * 32 + lq * 8];
            #pragma unroll
            for (int j = 0; j < 4; ++j) {
                bf16x8 bb = *(bf16x8*)&Ws[(j * 16 + lr) * 72 + ks * 32 + lq * 8];
                acc[0][j] = __builtin_amdgcn_mfma_f32_16x16x32_bf16(a0, bb, acc[0][j], 0, 0, 0);
                acc[1][j] = __builtin_amdgcn_mfma_f32_16x16x32_bf16(a1, bb, acc[1][j], 0, 0, 0);
            }
        }
    }

    float cs[4] = {}, cq[4] = {};
    #pragma unroll
    for (int m = 0; m < 2; ++m)
        #pragma unroll
        for (int j = 0; j < 4; ++j)
            #pragma unroll
            for (int r = 0; r < 4; ++r) {
                float v = acc[m][j][r];
                C[(size_t)(m0 + w * 32 + m * 16 + lq * 4 + r) * 256 + n0 + j * 16 + lr] = v;
                cs[j] += v;
                cq[j] += v * v;
            }
    #pragma unroll
    for (int j = 0; j < 4; ++j) {
        cs[j] += __shfl_xor(cs[j], 16); cs[j] += __shfl_xor(cs[j], 32);
        cq[j] += __shfl_xor(cq[j], 16); cq[j] += __shfl_xor(cq[j], 32);
    }
    __syncthreads();
    float* red = (float*)As;
    if (lq == 0) {
        #pragma unroll
        for (int j = 0; j < 4; ++j) {
            red[w * 128 + j * 16 + lr]      = cs[j];
            red[w * 128 + 64 + j * 16 + lr] = cq[j];
        }
    }
    __syncthreads();
    if (tid < 128) {
        int col = tid & 63, stat = tid >> 6;
        float t = red[stat * 64 + col] + red[128 + stat * 64 + col] +
                  red[256 + stat * 64 + col] + red[384 + stat * 64 + col];
        atomicAdd((stat ? gsumsq : gsum) + n0 + col, t);
    }
}

// ---------------------------------------------------------------------------
// Normalize + affine + LeakyReLU
// ---------------------------------------------------------------------------
__global__ __launch_bounds__(256) void bn_norm4(const float* __restrict__ p,
                                                const float* __restrict__ gsum,
                                                const float* __restrict__ gsumsq,
                                                const float* __restrict__ gamma,
                                                const float* __restrict__ beta,
                                                float* __restrict__ out) {
    int i = blockIdx.x * 256 + threadIdx.x;
    int c0 = (i * 4) & 255;
    const float invN = 1.0f / (float)NROWS;
    float4 pv = *(const float4*)(p + (size_t)i * 4);
    float vals[4] = {pv.x, pv.y, pv.z, pv.w};
    float res[4];
    #pragma unroll
    for (int k = 0; k < 4; ++k) {
        int c = c0 + k;
        float mean = gsum[c] * invN;
        float var  = gsumsq[c] * invN - mean * mean;
        float v = (vals[k] - mean) * rsqrtf(var + BN_EPS) * gamma[c] + beta[c];
        res[k] = v >= 0.f ? v : NEG_SLOPE * v;
    }
    float4 ov = {res[0], res[1], res[2], res[3]};
    *(float4*)(out + (size_t)i * 4) = ov;
}

// ---------------------------------------------------------------------------
// kernel_launch
// ---------------------------------------------------------------------------
extern "C" void kernel_launch(void* const* d_in, const int* in_sizes, int n_in,
                              void* d_out, int out_size, void* d_ws, size_t ws_size,
                              hipStream_t stream) {
    const float* x     = (const float*)d_in[0];
    const float* q     = (const float*)d_in[1];
    const float* Wq    = (const float*)d_in[2];
    const float* Wk    = (const float*)d_in[3];
    const float* Wv    = (const float*)d_in[4];
    const float* Wp    = (const float*)d_in[5];
    const float* gamma = (const float*)d_in[6];
    const float* beta  = (const float*)d_in[7];
    float* out = (float*)d_out;

    char* base = (char*)d_ws;
    unsigned short* Wqb  = (unsigned short*)(base + 0);          //  512x256 bf16
    unsigned short* Wkvb = (unsigned short*)(base + 262144);     // 1024x256 bf16
    unsigned short* Wpb  = (unsigned short*)(base + 786432);     //  256x512 bf16
    unsigned short* qh   = (unsigned short*)(base + 1048576);    // 16384x512 bf16
    unsigned short* khb  = (unsigned short*)(base + 17825792);   // 16384x512 bf16
    unsigned short* vTb  = (unsigned short*)(base + 34603008);   // [16,8,64,1024] bf16
    unsigned short* ob   = (unsigned short*)(base + 51380224);   // 16384x512 bf16
    float*          pbuf = (float*)        (base + 68157440);    // 16384x256 f32
    float*          stats= (float*)        (base + 84934656);    // 512 f32

    wcast<<<512, 256, 0, stream>>>(Wq, Wk, Wv, Wp, Wqb, Wkvb, Wpb, stats);

    gemm_qkv6<<<dim3(12, 128), 256, 0, stream>>>(q, x, Wqb, Wkvb, qh, khb, vTb);

    attn_mfma9<<<dim3(4, 8, 16), 256, 0, stream>>>(qh, khb, vTb, ob);

    gemm_out<<<dim3(4, 128), 256, 0, stream>>>(ob, Wpb, pbuf, stats, stats + 256);

    bn_norm4<<<4096, 256, 0, stream>>>(pbuf, stats, stats + 256, gamma, beta, out);
}

// Round 4
// 248.282 us; speedup vs baseline: 1.0683x; 1.0683x over previous
//
#include <hip/hip_runtime.h>
#include <cstddef>

#define B_    16
#define SQ_   1024
#define SE_   1024
#define CIN_  256
#define DK_   64
#define H_    8
#define HD_   512
#define NROWS 16384
#define BN_EPS 1e-5f
#define NEG_SLOPE 0.01f

typedef __attribute__((ext_vector_type(8))) short bf16x8;
typedef __attribute__((ext_vector_type(4))) float f32x4;

__device__ __forceinline__ unsigned short f2bf(float f) {  // RNE
    unsigned int u = __float_as_uint(f);
    return (unsigned short)((u + 0x7FFFu + ((u >> 16) & 1u)) >> 16);
}

#if __has_builtin(__builtin_amdgcn_perm)
__device__ __forceinline__ unsigned int pack_trunc(float lo, float hi) {
    return __builtin_amdgcn_perm(__float_as_uint(hi), __float_as_uint(lo), 0x07060302u);
}
#else
__device__ __forceinline__ unsigned int pack_trunc(float lo, float hi) {
    return (__float_as_uint(lo) >> 16) | (__float_as_uint(hi) & 0xFFFF0000u);
}
#endif

#if __has_builtin(__builtin_amdgcn_exp2f)
#define EXP2F(x) __builtin_amdgcn_exp2f(x)
#else
#define EXP2F(x) exp2f(x)
#endif

__device__ __forceinline__ ushort4 pack4(f32x4 v) {
    ushort4 p;
    p.x = f2bf(v[0]); p.y = f2bf(v[1]);
    p.z = f2bf(v[2]); p.w = f2bf(v[3]);
    return p;
}

// ---------------------------------------------------------------------------
// Weight casts (one dispatch). Wq gets 0.125*log2(e) folded in.
// Blocks 0..1 also zero the BN stats accumulators.
// ---------------------------------------------------------------------------
__global__ __launch_bounds__(256) void wcast(const float* __restrict__ Wq,
                                             const float* __restrict__ Wk,
                                             const float* __restrict__ Wv,
                                             const float* __restrict__ Wp,
                                             unsigned short* __restrict__ dWq,
                                             unsigned short* __restrict__ dWkv,
                                             unsigned short* __restrict__ dWp,
                                             float* __restrict__ stats) {
    if (blockIdx.x < 2) stats[blockIdx.x * 256 + threadIdx.x] = 0.f;
    int i = blockIdx.x * 256 + threadIdx.x;
    int which = i >> 15, off = i & 32767;
    const float* s; unsigned short* d; float sc = 1.0f;
    if (which == 0)      { s = Wq; d = dWq; sc = 0.18033688011112042f; }
    else if (which == 1) { s = Wk; d = dWkv; }
    else if (which == 2) { s = Wv; d = dWkv + 131072; }
    else                 { s = Wp; d = dWp; }
    float4 v = *(const float4*)(s + (size_t)off * 4);
    ushort4 pk;
    pk.x = f2bf(v.x * sc); pk.y = f2bf(v.y * sc);
    pk.z = f2bf(v.z * sc); pk.w = f2bf(v.w * sc);
    *(ushort4*)(d + (size_t)off * 4) = pk;
}

// ---------------------------------------------------------------------------
// Fused Q+KV projection GEMM, 128x128 tile, BK=64, f32 A with cast fused
// into LDS staging (no qbf/xbf intermediate), register prefetch.
// grid (12,128): bx<4 Q, 4..7 K, 8..11 V.
// Q/K: transposed compute mfma(W,A); V: normal compute (vT layout).
// Epilogue: LDS-staged full-line coalesced stores (R12 pattern).
// ---------------------------------------------------------------------------
__global__ __launch_bounds__(256) void gemm_qkv6(const float* __restrict__ qsrc,
                                                 const float* __restrict__ xsrc,
                                                 const unsigned short* __restrict__ Wqb,
                                                 const unsigned short* __restrict__ Wkvb,
                                                 unsigned short* __restrict__ qh,
                                                 unsigned short* __restrict__ khb,
                                                 unsigned short* __restrict__ vTb) {
    __shared__ __align__(16) unsigned short smem[18432];    // 36 KB
    unsigned short* As = smem;                              // 128*72
    unsigned short* Ws = smem + 9216;                       // 128*72
    unsigned short* Cs = smem;                              // epilogue: 128*144

    const int tid = threadIdx.x;
    const int w = tid >> 6, l = tid & 63, lq = l >> 4, lr = l & 15;
    const int bx = blockIdx.x;
    const bool isQ = bx < 4;
    const bool isV = bx >= 8;
    const float* A = isQ ? qsrc : xsrc;
    const unsigned short* W = isQ ? Wqb : Wkvb;
    const int n0 = (isQ ? bx : bx - 4) * 128;
    const int m0 = blockIdx.y * 128;
    const int K = 256;

    const int srow = tid >> 1, soff = (tid & 1) * 32;   // 32 elems/thread

    f32x4 acc[2][8] = {};
    uint4 aR[8], wR[4];

    {
        const float* Ar = A + (size_t)(m0 + srow) * K + soff;
        #pragma unroll
        for (int c = 0; c < 8; ++c) aR[c] = *(const uint4*)(Ar + c * 4);
        const unsigned short* Wr = W + (size_t)(n0 + srow) * K + soff;
        #pragma unroll
        for (int c = 0; c < 4; ++c) wR[c] = *(const uint4*)(Wr + c * 8);
    }

    for (int k0 = 0; k0 < K; k0 += 64) {
        __syncthreads();
        #pragma unroll
        for (int c = 0; c < 4; ++c) {
            float4 u0 = *(float4*)&aR[2 * c];
            float4 u1 = *(float4*)&aR[2 * c + 1];
            uint4 pk;
            pk.x = pack_trunc(u0.x, u0.y);
            pk.y = pack_trunc(u0.z, u0.w);
            pk.z = pack_trunc(u1.x, u1.y);
            pk.w = pack_trunc(u1.z, u1.w);
            *(uint4*)&As[srow * 72 + soff + c * 8] = pk;
            *(uint4*)&Ws[srow * 72 + soff + c * 8] = wR[c];
        }
        if (k0 + 64 < K) {
            const float* Ar = A + (size_t)(m0 + srow) * K + k0 + 64 + soff;
            #pragma unroll
            for (int c = 0; c < 8; ++c) aR[c] = *(const uint4*)(Ar + c * 4);
            const unsigned short* Wr = W + (size_t)(n0 + srow) * K + k0 + 64 + soff;
            #pragma unroll
            for (int c = 0; c < 4; ++c) wR[c] = *(const uint4*)(Wr + c * 8);
        }
        __syncthreads();

        if (!isV) {   // transposed compute: D[n][m]
            #pragma unroll
            for (int ks = 0; ks < 2; ++ks) {
                bf16x8 a0 = *(bf16x8*)&As[(w * 32 + lr) * 72 + ks * 32 + lq * 8];
                bf16x8 a1 = *(bf16x8*)&As[(w * 32 + 16 + lr) * 72 + ks * 32 + lq * 8];
                #pragma unroll
                for (int j = 0; j < 8; ++j) {
                    bf16x8 bb = *(bf16x8*)&Ws[(j * 16 + lr) * 72 + ks * 32 + lq * 8];
                    acc[0][j] = __builtin_amdgcn_mfma_f32_16x16x32_bf16(bb, a0, acc[0][j], 0, 0, 0);
                    acc[1][j] = __builtin_amdgcn_mfma_f32_16x16x32_bf16(bb, a1, acc[1][j], 0, 0, 0);
                }
            }
        } else {      // normal compute: D[m][n]
            #pragma unroll
            for (int ks = 0; ks < 2; ++ks) {
                bf16x8 a0 = *(bf16x8*)&As[(w * 32 + lr) * 72 + ks * 32 + lq * 8];
                bf16x8 a1 = *(bf16x8*)&As[(w * 32 + 16 + lr) * 72 + ks * 32 + lq * 8];
                #pragma unroll
                for (int j = 0; j < 8; ++j) {
                    bf16x8 bb = *(bf16x8*)&Ws[(j * 16 + lr) * 72 + ks * 32 + lq * 8];
                    acc[0][j] = __builtin_amdgcn_mfma_f32_16x16x32_bf16(a0, bb, acc[0][j], 0, 0, 0);
                    acc[1][j] = __builtin_amdgcn_mfma_f32_16x16x32_bf16(a1, bb, acc[1][j], 0, 0, 0);
                }
            }
        }
    }

    // ---- Epilogue: LDS staging, then full-line coalesced stores ----
    __syncthreads();
    const int c16 = tid & 15;
    const int rb  = tid >> 4;
    if (!isV) {
        #pragma unroll
        for (int mf = 0; mf < 2; ++mf)
            #pragma unroll
            for (int j = 0; j < 8; ++j)
                *(ushort4*)&Cs[(w * 32 + mf * 16 + lr) * 144 + j * 16 + lq * 4] =
                    pack4(acc[mf][j]);
        __syncthreads();
        unsigned short* C = isQ ? qh : khb;
        #pragma unroll
        for (int it = 0; it < 8; ++it) {
            int r = it * 16 + rb;
            *(uint4*)(C + (size_t)(m0 + r) * 512 + n0 + c16 * 8) =
                *(const uint4*)(Cs + r * 144 + c16 * 8);
        }
    } else {
        #pragma unroll
        for (int mf = 0; mf < 2; ++mf)
            #pragma unroll
            for (int j = 0; j < 8; ++j)
                *(ushort4*)&Cs[(j * 16 + lr) * 144 + w * 32 + mf * 16 + lq * 4] =
                    pack4(acc[mf][j]);
        __syncthreads();
        const int bb = m0 >> 10, t0 = m0 & 1023;
        #pragma unroll
        for (int it = 0; it < 8; ++it) {
            int el = it * 16 + rb;
            int colv = n0 - 512 + el;
            int hh = colv >> 6, e = colv & 63;
            *(uint4*)(vTb + (size_t)((bb * 8 + hh) * 64 + e) * 1024 + t0 + c16 * 8) =
                *(const uint4*)(Cs + el * 144 + c16 * 8);
        }
    }
}

// ---------------------------------------------------------------------------
// MFMA flash attention v10: half-split pipeline.
// Per 64-key tile: QK^T(h0) -> exp0/P0-write -> QK^T(h1) [overlaps P0 write
// latency] -> wait -> PV(h0) [MFMAs overlap exp1 VALU] -> exp1/P1-write ->
// wait -> PV(h1). Takes the P LDS round-trip and half the exp2 chain off
// the critical path (we are latency-bound: grid=512 blocks = 2/CU fixed).
// Ks/Vs: XOR-swizzled stride-64 (8 KB each); Ps: [64][40] per wave (20 KB).
// Total LDS 36.9 KB. P buffer reuse across halves is WAR-safe: PV(h0) MFMAs
// consume pf before P1 ds_writes issue (in-order issue + compiler waitcnt).
// ---------------------------------------------------------------------------
__global__ __launch_bounds__(256) void attn_mfma10(const unsigned short* __restrict__ qh,
                                                   const unsigned short* __restrict__ kh,
                                                   const unsigned short* __restrict__ vT,
                                                   unsigned short* __restrict__ o) {
    __shared__ __align__(16) unsigned short Ks[64 * 64];      // swizzled  8 KB
    __shared__ __align__(16) unsigned short Vs[64 * 64];      // swizzled  8 KB
    __shared__ __align__(16) unsigned short Ps[4][64 * 40];   // per-wave 20 KB

    const int tid = threadIdx.x;
    const int w = tid >> 6, l = tid & 63, lq = l >> 4, lr = l & 15;
    const int q0 = blockIdx.x * 256, h = blockIdx.y, b = blockIdx.z;
    const int swz = (lr & 7) << 3;            // XOR swizzle for K/V reads (shorts)

    // Q fragments: lane lr holds row m = mm*16+lr, elems k = lq*8+j (+32)
    bf16x8 qf[4][2];
    #pragma unroll
    for (int mm = 0; mm < 4; ++mm) {
        const unsigned short* qr =
            qh + (size_t)(b * SQ_ + q0 + w * 64 + mm * 16 + lr) * HD_ + h * DK_;
        qf[mm][0] = *(const bf16x8*)(qr + lq * 8);
        qf[mm][1] = *(const bf16x8*)(qr + 32 + lq * 8);
    }

    const unsigned short* kb = kh + (size_t)(b * SE_) * HD_ + h * DK_;
    const unsigned short* vb = vT + (size_t)((b * 8 + h) * 64) * 1024;

    const int se = tid >> 3;                  // 0..31
    const int sc = (tid & 7) * 8;
    const int sswz = (se & 7) << 3;           // staging-write swizzle (rr&7 == se&7)

    float l_i[4] = {};                        // per-lane partial row-sum
    f32x4 oacc[4][4] = {};                    // [mm][e-strip j]; D[e][m]
    unsigned short* Pw = Ps[w];

    // ---- prefetch K/V tile 0 into registers ----
    uint4 kR[2], vR[2];
    #pragma unroll
    for (int ps = 0; ps < 2; ++ps) {
        int rr = se + ps * 32;
        kR[ps] = *(const uint4*)(kb + (size_t)rr * HD_ + sc);
        vR[ps] = *(const uint4*)(vb + (size_t)rr * 1024 + sc);
    }

    for (int t0 = 0; t0 < SE_; t0 += 64) {
        __syncthreads();
        // write current tile (regs -> LDS, swizzled); vmcnt wait lands here
        #pragma unroll
        for (int ps = 0; ps < 2; ++ps) {
            int rr = se + ps * 32;
            int ad = ((rr * 64 + sc) ^ sswz);
            *(uint4*)&Ks[ad] = kR[ps];
            *(uint4*)&Vs[ad] = vR[ps];
        }
        // issue next tile's loads (no wait) -- latency hides under compute
        if (t0 + 64 < SE_) {
            #pragma unroll
            for (int ps = 0; ps < 2; ++ps) {
                int rr = se + ps * 32;
                kR[ps] = *(const uint4*)(kb + (size_t)(t0 + 64 + rr) * HD_ + sc);
                vR[ps] = *(const uint4*)(vb + (size_t)rr * 1024 + t0 + 64 + sc);
            }
        }
        __syncthreads();

        // ---- QK^T half 0: keys t0..t0+31 ----
        f32x4 s0[2][4] = {};
        __builtin_amdgcn_s_setprio(1);
        #pragma unroll
        for (int ks = 0; ks < 2; ++ks)
            #pragma unroll
            for (int tt = 0; tt < 2; ++tt) {
                bf16x8 kf = *(bf16x8*)&Ks[((tt * 16 + lr) * 64 + ks * 32 + lq * 8) ^ swz];
                #pragma unroll
                for (int mm = 0; mm < 4; ++mm)
                    s0[tt][mm] = __builtin_amdgcn_mfma_f32_16x16x32_bf16(kf, qf[mm][ks], s0[tt][mm], 0, 0, 0);
            }
        __builtin_amdgcn_s_setprio(0);

        // exp0 + P0 write (t-local cols 0..31)
        #pragma unroll
        for (int mm = 0; mm < 4; ++mm)
            #pragma unroll
            for (int tt = 0; tt < 2; ++tt) {
                float e0 = EXP2F(s0[tt][mm][0]);
                float e1 = EXP2F(s0[tt][mm][1]);
                float e2 = EXP2F(s0[tt][mm][2]);
                float e3 = EXP2F(s0[tt][mm][3]);
                l_i[mm] += (e0 + e1) + (e2 + e3);
                uint2 pk;
                pk.x = pack_trunc(e0, e1);
                pk.y = pack_trunc(e2, e3);
                *(uint2*)&Pw[(mm * 16 + lr) * 40 + tt * 16 + lq * 4] = pk;
            }

        // ---- QK^T half 1: keys t0+32..t0+63 (overlaps P0 write latency) ----
        f32x4 s1[2][4] = {};
        __builtin_amdgcn_s_setprio(1);
        #pragma unroll
        for (int ks = 0; ks < 2; ++ks)
            #pragma unroll
            for (int tt = 0; tt < 2; ++tt) {
                bf16x8 kf = *(bf16x8*)&Ks[(((tt + 2) * 16 + lr) * 64 + ks * 32 + lq * 8) ^ swz];
                #pragma unroll
                for (int mm = 0; mm < 4; ++mm)
                    s1[tt][mm] = __builtin_amdgcn_mfma_f32_16x16x32_bf16(kf, qf[mm][ks], s1[tt][mm], 0, 0, 0);
            }
        __builtin_amdgcn_s_setprio(0);

        asm volatile("s_waitcnt lgkmcnt(0)" ::: "memory");   // P0 writes done

        // ---- PV half 0: V cols t0..t0+31 (MFMAs overlap exp1 below) ----
        __builtin_amdgcn_s_setprio(1);
        {
            bf16x8 pf[4];
            #pragma unroll
            for (int mm = 0; mm < 4; ++mm)
                pf[mm] = *(bf16x8*)&Pw[(mm * 16 + lr) * 40 + lq * 8];
            #pragma unroll
            for (int j = 0; j < 4; ++j) {
                bf16x8 vf = *(bf16x8*)&Vs[((j * 16 + lr) * 64 + lq * 8) ^ swz];
                #pragma unroll
                for (int mm = 0; mm < 4; ++mm)
                    oacc[mm][j] = __builtin_amdgcn_mfma_f32_16x16x32_bf16(vf, pf[mm], oacc[mm][j], 0, 0, 0);
            }
        }
        __builtin_amdgcn_s_setprio(0);

        // exp1 + P1 write (reuses P slots; WAR-safe, see header comment)
        #pragma unroll
        for (int mm = 0; mm < 4; ++mm)
            #pragma unroll
            for (int tt = 0; tt < 2; ++tt) {
                float e0 = EXP2F(s1[tt][mm][0]);
                float e1 = EXP2F(s1[tt][mm][1]);
                float e2 = EXP2F(s1[tt][mm][2]);
                float e3 = EXP2F(s1[tt][mm][3]);
                l_i[mm] += (e0 + e1) + (e2 + e3);
                uint2 pk;
                pk.x = pack_trunc(e0, e1);
                pk.y = pack_trunc(e2, e3);
                *(uint2*)&Pw[(mm * 16 + lr) * 40 + tt * 16 + lq * 4] = pk;
            }

        asm volatile("s_waitcnt lgkmcnt(0)" ::: "memory");   // P1 writes done

        // ---- PV half 1: V cols t0+32..t0+63 ----
        __builtin_amdgcn_s_setprio(1);
        {
            bf16x8 pf[4];
            #pragma unroll
            for (int mm = 0; mm < 4; ++mm)
                pf[mm] = *(bf16x8*)&Pw[(mm * 16 + lr) * 40 + lq * 8];
            #pragma unroll
            for (int j = 0; j < 4; ++j) {
                bf16x8 vf = *(bf16x8*)&Vs[((j * 16 + lr) * 64 + 32 + lq * 8) ^ swz];
                #pragma unroll
                for (int mm = 0; mm < 4; ++mm)
                    oacc[mm][j] = __builtin_amdgcn_mfma_f32_16x16x32_bf16(vf, pf[mm], oacc[mm][j], 0, 0, 0);
            }
        }
        __builtin_amdgcn_s_setprio(0);
    }

    float inv[4];
    #pragma unroll
    for (int mm = 0; mm < 4; ++mm) {
        float t = l_i[mm];
        t += __shfl_xor(t, 16);
        t += __shfl_xor(t, 32);
        inv[mm] = 1.0f / t;
    }

    // o store: D row = e_local = lq*4+r (4 consecutive e), col = m = lr.
    #pragma unroll
    for (int mm = 0; mm < 4; ++mm)
        #pragma unroll
        for (int j = 0; j < 4; ++j) {
            f32x4 v = oacc[mm][j];
            v[0] *= inv[mm]; v[1] *= inv[mm]; v[2] *= inv[mm]; v[3] *= inv[mm];
            *(ushort4*)&o[(size_t)(b * SQ_ + q0 + w * 64 + mm * 16 + lr) * HD_ +
                          h * DK_ + j * 16 + lq * 4] = pack4(v);
        }
}

// ---------------------------------------------------------------------------
// Output projection: p = o @ Wp^T (bf16 in, f32 out) + fused BN partials.
// 128x64 tiles, K=512, register prefetch.
// ---------------------------------------------------------------------------
__global__ __launch_bounds__(256) void gemm_out(const unsigned short* __restrict__ A,
                                                const unsigned short* __restrict__ W,
                                                float* __restrict__ C,
                                                float* __restrict__ gsum,
                                                float* __restrict__ gsumsq) {
    __shared__ __align__(16) unsigned short As[128 * 72];
    __shared__ __align__(16) unsigned short Ws[64 * 72];
    const int tid = threadIdx.x;
    const int w = tid >> 6, l = tid & 63, lq = l >> 4, lr = l & 15;
    const int n0 = blockIdx.x * 64, m0 = blockIdx.y * 128;
    const int K = 512;

    const int arow = tid >> 1, aoff = (tid & 1) * 32;
    const int wrow = tid >> 2, woff = (tid & 3) * 16;

    f32x4 acc[2][4] = {};
    uint4 aR[4], wR[2];

    {
        const unsigned short* Ar = A + (size_t)(m0 + arow) * K + aoff;
        #pragma unroll
        for (int c = 0; c < 4; ++c) aR[c] = *(const uint4*)(Ar + c * 8);
        const unsigned short* Wr = W + (size_t)(n0 + wrow) * K + woff;
        #pragma unroll
        for (int c = 0; c < 2; ++c) wR[c] = *(const uint4*)(Wr + c * 8);
    }

    for (int k0 = 0; k0 < K; k0 += 64) {
        __syncthreads();
        #pragma unroll
        for (int c = 0; c < 4; ++c)
            *(uint4*)&As[arow * 72 + aoff + c * 8] = aR[c];
        #pragma unroll
        for (int c = 0; c < 2; ++c)
            *(uint4*)&Ws[wrow * 72 + woff + c * 8] = wR[c];

        if (k0 + 64 < K) {
            const unsigned short* Ar = A + (size_t)(m0 + arow) * K + k0 + 64 + aoff;
            #pragma unroll
            for (int c = 0; c < 4; ++c) aR[c] = *(const uint4*)(Ar + c * 8);
            const unsigned short* Wr = W + (size_t)(n0 + wrow) * K + k0 + 64 + woff;
            #pragma unroll
            for (int c = 0; c < 2; ++c) wR[c] = *(const uint4*)(Wr + c * 8);
        }
        __syncthreads();

        #pragma unroll
        for (int ks = 0; ks < 2; ++ks) {
            bf16x8 a0 = *(bf16x8*)&As[(w * 32 + lr) * 72 + ks * 32 + lq * 8];
            bf16x8 a1 = *(bf16x8*)&As[(w * 32 + 16 + lr) * 72 + ks * 32 + lq * 8];
            #pragma unroll
            for (int j = 0; j < 4; ++j) {
                bf16x8 bb = *(bf16x8*)&Ws[(j * 16 + lr) * 72 + ks * 32 + lq * 8];
                acc[0][j] = __builtin_amdgcn_mfma_f32_16x16x32_bf16(a0, bb, acc[0][j], 0, 0, 0);
                acc[1][j] = __builtin_amdgcn_mfma_f32_16x16x32_bf16(a1, bb, acc[1][j], 0, 0, 0);
            }
        }
    }

    float cs[4] = {}, cq[4] = {};
    #pragma unroll
    for (int m = 0; m < 2; ++m)
        #pragma unroll
        for (int j = 0; j < 4; ++j)
            #pragma unroll
            for (int r = 0; r < 4; ++r) {
                float v = acc[m][j][r];
                C[(size_t)(m0 + w * 32 + m * 16 + lq * 4 + r) * 256 + n0 + j * 16 + lr] = v;
                cs[j] += v;
                cq[j] += v * v;
            }
    #pragma unroll
    for (int j = 0; j < 4; ++j) {
        cs[j] += __shfl_xor(cs[j], 16); cs[j] += __shfl_xor(cs[j], 32);
        cq[j] += __shfl_xor(cq[j], 16); cq[j] += __shfl_xor(cq[j], 32);
    }
    __syncthreads();
    float* red = (float*)As;
    if (lq == 0) {
        #pragma unroll
        for (int j = 0; j < 4; ++j) {
            red[w * 128 + j * 16 + lr]      = cs[j];
            red[w * 128 + 64 + j * 16 + lr] = cq[j];
        }
    }
    __syncthreads();
    if (tid < 128) {
        int col = tid & 63, stat = tid >> 6;
        float t = red[stat * 64 + col] + red[128 + stat * 64 + col] +
                  red[256 + stat * 64 + col] + red[384 + stat * 64 + col];
        atomicAdd((stat ? gsumsq : gsum) + n0 + col, t);
    }
}

// ---------------------------------------------------------------------------
// Normalize + affine + LeakyReLU
// ---------------------------------------------------------------------------
__global__ __launch_bounds__(256) void bn_norm4(const float* __restrict__ p,
                                                const float* __restrict__ gsum,
                                                const float* __restrict__ gsumsq,
                                                const float* __restrict__ gamma,
                                                const float* __restrict__ beta,
                                                float* __restrict__ out) {
    int i = blockIdx.x * 256 + threadIdx.x;
    int c0 = (i * 4) & 255;
    const float invN = 1.0f / (float)NROWS;
    float4 pv = *(const float4*)(p + (size_t)i * 4);
    float vals[4] = {pv.x, pv.y, pv.z, pv.w};
    float res[4];
    #pragma unroll
    for (int k = 0; k < 4; ++k) {
        int c = c0 + k;
        float mean = gsum[c] * invN;
        float var  = gsumsq[c] * invN - mean * mean;
        float v = (vals[k] - mean) * rsqrtf(var + BN_EPS) * gamma[c] + beta[c];
        res[k] = v >= 0.f ? v : NEG_SLOPE * v;
    }
    float4 ov = {res[0], res[1], res[2], res[3]};
    *(float4*)(out + (size_t)i * 4) = ov;
}

// ---------------------------------------------------------------------------
// kernel_launch
// ---------------------------------------------------------------------------
extern "C" void kernel_launch(void* const* d_in, const int* in_sizes, int n_in,
                              void* d_out, int out_size, void* d_ws, size_t ws_size,
                              hipStream_t stream) {
    const float* x     = (const float*)d_in[0];
    const float* q     = (const float*)d_in[1];
    const float* Wq    = (const float*)d_in[2];
    const float* Wk    = (const float*)d_in[3];
    const float* Wv    = (const float*)d_in[4];
    const float* Wp    = (const float*)d_in[5];
    const float* gamma = (const float*)d_in[6];
    const float* beta  = (const float*)d_in[7];
    float* out = (float*)d_out;

    char* base = (char*)d_ws;
    unsigned short* Wqb  = (unsigned short*)(base + 0);          //  512x256 bf16
    unsigned short* Wkvb = (unsigned short*)(base + 262144);     // 1024x256 bf16
    unsigned short* Wpb  = (unsigned short*)(base + 786432);     //  256x512 bf16
    unsigned short* qh   = (unsigned short*)(base + 1048576);    // 16384x512 bf16
    unsigned short* khb  = (unsigned short*)(base + 17825792);   // 16384x512 bf16
    unsigned short* vTb  = (unsigned short*)(base + 34603008);   // [16,8,64,1024] bf16
    unsigned short* ob   = (unsigned short*)(base + 51380224);   // 16384x512 bf16
    float*          pbuf = (float*)        (base + 68157440);    // 16384x256 f32
    float*          stats= (float*)        (base + 84934656);    // 512 f32

    wcast<<<512, 256, 0, stream>>>(Wq, Wk, Wv, Wp, Wqb, Wkvb, Wpb, stats);

    gemm_qkv6<<<dim3(12, 128), 256, 0, stream>>>(q, x, Wqb, Wkvb, qh, khb, vTb);

    attn_mfma10<<<dim3(4, 8, 16), 256, 0, stream>>>(qh, khb, vTb, ob);

    gemm_out<<<dim3(4, 128), 256, 0, stream>>>(ob, Wpb, pbuf, stats, stats + 256);

    bn_norm4<<<4096, 256, 0, stream>>>(pbuf, stats, stats + 256, gamma, beta, out);
}

// Round 5
// 243.127 us; speedup vs baseline: 1.0910x; 1.0212x over previous
//
#include <hip/hip_runtime.h>
#include <cstddef>

#define B_    16
#define SQ_   1024
#define SE_   1024
#define CIN_  256
#define DK_   64
#define H_    8
#define HD_   512
#define NROWS 16384
#define BN_EPS 1e-5f
#define NEG_SLOPE 0.01f

typedef __attribute__((ext_vector_type(8))) short bf16x8;
typedef __attribute__((ext_vector_type(4))) float f32x4;

__device__ __forceinline__ unsigned short f2bf(float f) {  // RNE
    unsigned int u = __float_as_uint(f);
    return (unsigned short)((u + 0x7FFFu + ((u >> 16) & 1u)) >> 16);
}

#if __has_builtin(__builtin_amdgcn_perm)
__device__ __forceinline__ unsigned int pack_trunc(float lo, float hi) {
    return __builtin_amdgcn_perm(__float_as_uint(hi), __float_as_uint(lo), 0x07060302u);
}
#else
__device__ __forceinline__ unsigned int pack_trunc(float lo, float hi) {
    return (__float_as_uint(lo) >> 16) | (__float_as_uint(hi) & 0xFFFF0000u);
}
#endif

#if __has_builtin(__builtin_amdgcn_exp2f)
#define EXP2F(x) __builtin_amdgcn_exp2f(x)
#else
#define EXP2F(x) exp2f(x)
#endif

__device__ __forceinline__ ushort4 pack4(f32x4 v) {
    ushort4 p;
    p.x = f2bf(v[0]); p.y = f2bf(v[1]);
    p.z = f2bf(v[2]); p.w = f2bf(v[3]);
    return p;
}

// ---------------------------------------------------------------------------
// Weight casts (one dispatch). Wq gets 0.125*log2(e) folded in.
// Blocks 0..1 also zero the BN stats accumulators.
// ---------------------------------------------------------------------------
__global__ __launch_bounds__(256) void wcast(const float* __restrict__ Wq,
                                             const float* __restrict__ Wk,
                                             const float* __restrict__ Wv,
                                             const float* __restrict__ Wp,
                                             unsigned short* __restrict__ dWq,
                                             unsigned short* __restrict__ dWkv,
                                             unsigned short* __restrict__ dWp,
                                             float* __restrict__ stats) {
    if (blockIdx.x < 2) stats[blockIdx.x * 256 + threadIdx.x] = 0.f;
    int i = blockIdx.x * 256 + threadIdx.x;
    int which = i >> 15, off = i & 32767;
    const float* s; unsigned short* d; float sc = 1.0f;
    if (which == 0)      { s = Wq; d = dWq; sc = 0.18033688011112042f; }
    else if (which == 1) { s = Wk; d = dWkv; }
    else if (which == 2) { s = Wv; d = dWkv + 131072; }
    else                 { s = Wp; d = dWp; }
    float4 v = *(const float4*)(s + (size_t)off * 4);
    ushort4 pk;
    pk.x = f2bf(v.x * sc); pk.y = f2bf(v.y * sc);
    pk.z = f2bf(v.z * sc); pk.w = f2bf(v.w * sc);
    *(ushort4*)(d + (size_t)off * 4) = pk;
}

// ---------------------------------------------------------------------------
// Fused Q+KV projection GEMM, 128x128 tile, BK=64, f32 A with cast fused
// into LDS staging, register prefetch.
// 1-D grid of 1536 with XCD-aware decode: xcd = flat&7 (HW round-robin),
// j = flat>>3; bx = j%12, by = j/12 + xcd*16. All 12 bx-sharers of an
// A-panel (same by) land on ONE XCD -> A fetched once per XCD L2 instead
// of 8x from HBM (was FETCH=112MB, demand ~200MB).
// bx<4 Q, 4..7 K, 8..11 V. Q/K transposed compute; V normal (vT layout).
// ---------------------------------------------------------------------------
__global__ __launch_bounds__(256) void gemm_qkv7(const float* __restrict__ qsrc,
                                                 const float* __restrict__ xsrc,
                                                 const unsigned short* __restrict__ Wqb,
                                                 const unsigned short* __restrict__ Wkvb,
                                                 unsigned short* __restrict__ qh,
                                                 unsigned short* __restrict__ khb,
                                                 unsigned short* __restrict__ vTb) {
    __shared__ __align__(16) unsigned short smem[18432];    // 36 KB
    unsigned short* As = smem;                              // 128*72
    unsigned short* Ws = smem + 9216;                       // 128*72
    unsigned short* Cs = smem;                              // epilogue: 128*144

    const int tid = threadIdx.x;
    const int w = tid >> 6, l = tid & 63, lq = l >> 4, lr = l & 15;

    // XCD-aware decode (bijective: 1536 = 8 * 192, 192 = 12 * 16)
    const int flat = blockIdx.x;
    const int xcd  = flat & 7;
    const int jj   = flat >> 3;          // 0..191
    const int bx   = jj % 12;
    const int by   = (jj / 12) + xcd * 16;

    const bool isQ = bx < 4;
    const bool isV = bx >= 8;
    const float* A = isQ ? qsrc : xsrc;
    const unsigned short* W = isQ ? Wqb : Wkvb;
    const int n0 = (isQ ? bx : bx - 4) * 128;
    const int m0 = by * 128;
    const int K = 256;

    const int srow = tid >> 1, soff = (tid & 1) * 32;   // 32 elems/thread

    f32x4 acc[2][8] = {};
    uint4 aR[8], wR[4];

    {
        const float* Ar = A + (size_t)(m0 + srow) * K + soff;
        #pragma unroll
        for (int c = 0; c < 8; ++c) aR[c] = *(const uint4*)(Ar + c * 4);
        const unsigned short* Wr = W + (size_t)(n0 + srow) * K + soff;
        #pragma unroll
        for (int c = 0; c < 4; ++c) wR[c] = *(const uint4*)(Wr + c * 8);
    }

    for (int k0 = 0; k0 < K; k0 += 64) {
        __syncthreads();
        #pragma unroll
        for (int c = 0; c < 4; ++c) {
            float4 u0 = *(float4*)&aR[2 * c];
            float4 u1 = *(float4*)&aR[2 * c + 1];
            uint4 pk;
            pk.x = pack_trunc(u0.x, u0.y);
            pk.y = pack_trunc(u0.z, u0.w);
            pk.z = pack_trunc(u1.x, u1.y);
            pk.w = pack_trunc(u1.z, u1.w);
            *(uint4*)&As[srow * 72 + soff + c * 8] = pk;
            *(uint4*)&Ws[srow * 72 + soff + c * 8] = wR[c];
        }
        if (k0 + 64 < K) {
            const float* Ar = A + (size_t)(m0 + srow) * K + k0 + 64 + soff;
            #pragma unroll
            for (int c = 0; c < 8; ++c) aR[c] = *(const uint4*)(Ar + c * 4);
            const unsigned short* Wr = W + (size_t)(n0 + srow) * K + k0 + 64 + soff;
            #pragma unroll
            for (int c = 0; c < 4; ++c) wR[c] = *(const uint4*)(Wr + c * 8);
        }
        __syncthreads();

        if (!isV) {   // transposed compute: D[n][m]
            #pragma unroll
            for (int ks = 0; ks < 2; ++ks) {
                bf16x8 a0 = *(bf16x8*)&As[(w * 32 + lr) * 72 + ks * 32 + lq * 8];
                bf16x8 a1 = *(bf16x8*)&As[(w * 32 + 16 + lr) * 72 + ks * 32 + lq * 8];
                #pragma unroll
                for (int j = 0; j < 8; ++j) {
                    bf16x8 bb = *(bf16x8*)&Ws[(j * 16 + lr) * 72 + ks * 32 + lq * 8];
                    acc[0][j] = __builtin_amdgcn_mfma_f32_16x16x32_bf16(bb, a0, acc[0][j], 0, 0, 0);
                    acc[1][j] = __builtin_amdgcn_mfma_f32_16x16x32_bf16(bb, a1, acc[1][j], 0, 0, 0);
                }
            }
        } else {      // normal compute: D[m][n]
            #pragma unroll
            for (int ks = 0; ks < 2; ++ks) {
                bf16x8 a0 = *(bf16x8*)&As[(w * 32 + lr) * 72 + ks * 32 + lq * 8];
                bf16x8 a1 = *(bf16x8*)&As[(w * 32 + 16 + lr) * 72 + ks * 32 + lq * 8];
                #pragma unroll
                for (int j = 0; j < 8; ++j) {
                    bf16x8 bb = *(bf16x8*)&Ws[(j * 16 + lr) * 72 + ks * 32 + lq * 8];
                    acc[0][j] = __builtin_amdgcn_mfma_f32_16x16x32_bf16(a0, bb, acc[0][j], 0, 0, 0);
                    acc[1][j] = __builtin_amdgcn_mfma_f32_16x16x32_bf16(a1, bb, acc[1][j], 0, 0, 0);
                }
            }
        }
    }

    // ---- Epilogue: LDS staging, then full-line coalesced stores ----
    __syncthreads();
    const int c16 = tid & 15;
    const int rb  = tid >> 4;
    if (!isV) {
        #pragma unroll
        for (int mf = 0; mf < 2; ++mf)
            #pragma unroll
            for (int j = 0; j < 8; ++j)
                *(ushort4*)&Cs[(w * 32 + mf * 16 + lr) * 144 + j * 16 + lq * 4] =
                    pack4(acc[mf][j]);
        __syncthreads();
        unsigned short* C = isQ ? qh : khb;
        #pragma unroll
        for (int it = 0; it < 8; ++it) {
            int r = it * 16 + rb;
            *(uint4*)(C + (size_t)(m0 + r) * 512 + n0 + c16 * 8) =
                *(const uint4*)(Cs + r * 144 + c16 * 8);
        }
    } else {
        #pragma unroll
        for (int mf = 0; mf < 2; ++mf)
            #pragma unroll
            for (int j = 0; j < 8; ++j)
                *(ushort4*)&Cs[(j * 16 + lr) * 144 + w * 32 + mf * 16 + lq * 4] =
                    pack4(acc[mf][j]);
        __syncthreads();
        const int bb = m0 >> 10, t0 = m0 & 1023;
        #pragma unroll
        for (int it = 0; it < 8; ++it) {
            int el = it * 16 + rb;
            int colv = n0 - 512 + el;
            int hh = colv >> 6, e = colv & 63;
            *(uint4*)(vTb + (size_t)((bb * 8 + hh) * 64 + e) * 1024 + t0 + c16 * 8) =
                *(const uint4*)(Cs + el * 144 + c16 * 8);
        }
    }
}

// ---------------------------------------------------------------------------
// MFMA flash attention v11: v10 half-split pipeline + XCD-aware decode.
// 1-D grid 512: xcd = flat&7, j = flat>>3; the 4 q-blocks sharing a (b,h)
// K/V slice (256 KB) now land on one XCD -> K/V staging loads become
// same-XCD L2 hits instead of L3/HBM (~200 vs ~500-900 cyc).
// Per tile: QK^T(h0) -> exp0/P0 -> QK^T(h1) [overlaps P0 write] -> wait ->
// PV(h0) [overlaps exp1] -> exp1/P1 -> wait -> PV(h1). LDS 36.9 KB.
// ---------------------------------------------------------------------------
__global__ __launch_bounds__(256) void attn_mfma11(const unsigned short* __restrict__ qh,
                                                   const unsigned short* __restrict__ kh,
                                                   const unsigned short* __restrict__ vT,
                                                   unsigned short* __restrict__ o) {
    __shared__ __align__(16) unsigned short Ks[64 * 64];      // swizzled  8 KB
    __shared__ __align__(16) unsigned short Vs[64 * 64];      // swizzled  8 KB
    __shared__ __align__(16) unsigned short Ps[4][64 * 40];   // per-wave 20 KB

    const int tid = threadIdx.x;
    const int w = tid >> 6, l = tid & 63, lq = l >> 4, lr = l & 15;

    // XCD-aware decode (bijective: 512 = 8 * 64, 64 = 4 * 16)
    const int flat = blockIdx.x;
    const int xcd  = flat & 7;
    const int jj   = flat >> 3;          // 0..63
    const int q0   = (jj & 3) * 256;
    const int hb   = (jj >> 2) + xcd * 16;   // 0..127
    const int h    = hb & 7;
    const int b    = hb >> 3;

    const int swz = (lr & 7) << 3;            // XOR swizzle for K/V reads (shorts)

    // Q fragments: lane lr holds row m = mm*16+lr, elems k = lq*8+j (+32)
    bf16x8 qf[4][2];
    #pragma unroll
    for (int mm = 0; mm < 4; ++mm) {
        const unsigned short* qr =
            qh + (size_t)(b * SQ_ + q0 + w * 64 + mm * 16 + lr) * HD_ + h * DK_;
        qf[mm][0] = *(const bf16x8*)(qr + lq * 8);
        qf[mm][1] = *(const bf16x8*)(qr + 32 + lq * 8);
    }

    const unsigned short* kb = kh + (size_t)(b * SE_) * HD_ + h * DK_;
    const unsigned short* vb = vT + (size_t)((b * 8 + h) * 64) * 1024;

    const int se = tid >> 3;                  // 0..31
    const int sc = (tid & 7) * 8;
    const int sswz = (se & 7) << 3;           // staging-write swizzle (rr&7 == se&7)

    float l_i[4] = {};                        // per-lane partial row-sum
    f32x4 oacc[4][4] = {};                    // [mm][e-strip j]; D[e][m]
    unsigned short* Pw = Ps[w];

    // ---- prefetch K/V tile 0 into registers ----
    uint4 kR[2], vR[2];
    #pragma unroll
    for (int ps = 0; ps < 2; ++ps) {
        int rr = se + ps * 32;
        kR[ps] = *(const uint4*)(kb + (size_t)rr * HD_ + sc);
        vR[ps] = *(const uint4*)(vb + (size_t)rr * 1024 + sc);
    }

    for (int t0 = 0; t0 < SE_; t0 += 64) {
        __syncthreads();
        // write current tile (regs -> LDS, swizzled); vmcnt wait lands here
        #pragma unroll
        for (int ps = 0; ps < 2; ++ps) {
            int rr = se + ps * 32;
            int ad = ((rr * 64 + sc) ^ sswz);
            *(uint4*)&Ks[ad] = kR[ps];
            *(uint4*)&Vs[ad] = vR[ps];
        }
        // issue next tile's loads (no wait) -- latency hides under compute
        if (t0 + 64 < SE_) {
            #pragma unroll
            for (int ps = 0; ps < 2; ++ps) {
                int rr = se + ps * 32;
                kR[ps] = *(const uint4*)(kb + (size_t)(t0 + 64 + rr) * HD_ + sc);
                vR[ps] = *(const uint4*)(vb + (size_t)rr * 1024 + t0 + 64 + sc);
            }
        }
        __syncthreads();

        // ---- QK^T half 0: keys t0..t0+31 ----
        f32x4 s0[2][4] = {};
        __builtin_amdgcn_s_setprio(1);
        #pragma unroll
        for (int ks = 0; ks < 2; ++ks)
            #pragma unroll
            for (int tt = 0; tt < 2; ++tt) {
                bf16x8 kf = *(bf16x8*)&Ks[((tt * 16 + lr) * 64 + ks * 32 + lq * 8) ^ swz];
                #pragma unroll
                for (int mm = 0; mm < 4; ++mm)
                    s0[tt][mm] = __builtin_amdgcn_mfma_f32_16x16x32_bf16(kf, qf[mm][ks], s0[tt][mm], 0, 0, 0);
            }
        __builtin_amdgcn_s_setprio(0);

        // exp0 + P0 write (t-local cols 0..31)
        #pragma unroll
        for (int mm = 0; mm < 4; ++mm)
            #pragma unroll
            for (int tt = 0; tt < 2; ++tt) {
                float e0 = EXP2F(s0[tt][mm][0]);
                float e1 = EXP2F(s0[tt][mm][1]);
                float e2 = EXP2F(s0[tt][mm][2]);
                float e3 = EXP2F(s0[tt][mm][3]);
                l_i[mm] += (e0 + e1) + (e2 + e3);
                uint2 pk;
                pk.x = pack_trunc(e0, e1);
                pk.y = pack_trunc(e2, e3);
                *(uint2*)&Pw[(mm * 16 + lr) * 40 + tt * 16 + lq * 4] = pk;
            }

        // ---- QK^T half 1: keys t0+32..t0+63 (overlaps P0 write latency) ----
        f32x4 s1[2][4] = {};
        __builtin_amdgcn_s_setprio(1);
        #pragma unroll
        for (int ks = 0; ks < 2; ++ks)
            #pragma unroll
            for (int tt = 0; tt < 2; ++tt) {
                bf16x8 kf = *(bf16x8*)&Ks[(((tt + 2) * 16 + lr) * 64 + ks * 32 + lq * 8) ^ swz];
                #pragma unroll
                for (int mm = 0; mm < 4; ++mm)
                    s1[tt][mm] = __builtin_amdgcn_mfma_f32_16x16x32_bf16(kf, qf[mm][ks], s1[tt][mm], 0, 0, 0);
            }
        __builtin_amdgcn_s_setprio(0);

        asm volatile("s_waitcnt lgkmcnt(0)" ::: "memory");   // P0 writes done

        // ---- PV half 0: V cols t0..t0+31 (MFMAs overlap exp1 below) ----
        __builtin_amdgcn_s_setprio(1);
        {
            bf16x8 pf[4];
            #pragma unroll
            for (int mm = 0; mm < 4; ++mm)
                pf[mm] = *(bf16x8*)&Pw[(mm * 16 + lr) * 40 + lq * 8];
            #pragma unroll
            for (int j = 0; j < 4; ++j) {
                bf16x8 vf = *(bf16x8*)&Vs[((j * 16 + lr) * 64 + lq * 8) ^ swz];
                #pragma unroll
                for (int mm = 0; mm < 4; ++mm)
                    oacc[mm][j] = __builtin_amdgcn_mfma_f32_16x16x32_bf16(vf, pf[mm], oacc[mm][j], 0, 0, 0);
            }
        }
        __builtin_amdgcn_s_setprio(0);

        // exp1 + P1 write (reuses P slots; WAR-safe: PV(h0) reads issued first)
        #pragma unroll
        for (int mm = 0; mm < 4; ++mm)
            #pragma unroll
            for (int tt = 0; tt < 2; ++tt) {
                float e0 = EXP2F(s1[tt][mm][0]);
                float e1 = EXP2F(s1[tt][mm][1]);
                float e2 = EXP2F(s1[tt][mm][2]);
                float e3 = EXP2F(s1[tt][mm][3]);
                l_i[mm] += (e0 + e1) + (e2 + e3);
                uint2 pk;
                pk.x = pack_trunc(e0, e1);
                pk.y = pack_trunc(e2, e3);
                *(uint2*)&Pw[(mm * 16 + lr) * 40 + tt * 16 + lq * 4] = pk;
            }

        asm volatile("s_waitcnt lgkmcnt(0)" ::: "memory");   // P1 writes done

        // ---- PV half 1: V cols t0+32..t0+63 ----
        __builtin_amdgcn_s_setprio(1);
        {
            bf16x8 pf[4];
            #pragma unroll
            for (int mm = 0; mm < 4; ++mm)
                pf[mm] = *(bf16x8*)&Pw[(mm * 16 + lr) * 40 + lq * 8];
            #pragma unroll
            for (int j = 0; j < 4; ++j) {
                bf16x8 vf = *(bf16x8*)&Vs[((j * 16 + lr) * 64 + 32 + lq * 8) ^ swz];
                #pragma unroll
                for (int mm = 0; mm < 4; ++mm)
                    oacc[mm][j] = __builtin_amdgcn_mfma_f32_16x16x32_bf16(vf, pf[mm], oacc[mm][j], 0, 0, 0);
            }
        }
        __builtin_amdgcn_s_setprio(0);
    }

    float inv[4];
    #pragma unroll
    for (int mm = 0; mm < 4; ++mm) {
        float t = l_i[mm];
        t += __shfl_xor(t, 16);
        t += __shfl_xor(t, 32);
        inv[mm] = 1.0f / t;
    }

    // o store: D row = e_local = lq*4+r (4 consecutive e), col = m = lr.
    #pragma unroll
    for (int mm = 0; mm < 4; ++mm)
        #pragma unroll
        for (int j = 0; j < 4; ++j) {
            f32x4 v = oacc[mm][j];
            v[0] *= inv[mm]; v[1] *= inv[mm]; v[2] *= inv[mm]; v[3] *= inv[mm];
            *(ushort4*)&o[(size_t)(b * SQ_ + q0 + w * 64 + mm * 16 + lr) * HD_ +
                          h * DK_ + j * 16 + lq * 4] = pack4(v);
        }
}

// ---------------------------------------------------------------------------
// Output projection: p = o @ Wp^T (bf16 in, f32 out) + fused BN partials.
// 128x64 tiles, K=512, register prefetch.
// ---------------------------------------------------------------------------
__global__ __launch_bounds__(256) void gemm_out(const unsigned short* __restrict__ A,
                                                const unsigned short* __restrict__ W,
                                                float* __restrict__ C,
                                                float* __restrict__ gsum,
                                                float* __restrict__ gsumsq) {
    __shared__ __align__(16) unsigned short As[128 * 72];
    __shared__ __align__(16) unsigned short Ws[64 * 72];
    const int tid = threadIdx.x;
    const int w = tid >> 6, l = tid & 63, lq = l >> 4, lr = l & 15;
    const int n0 = blockIdx.x * 64, m0 = blockIdx.y * 128;
    const int K = 512;

    const int arow = tid >> 1, aoff = (tid & 1) * 32;
    const int wrow = tid >> 2, woff = (tid & 3) * 16;

    f32x4 acc[2][4] = {};
    uint4 aR[4], wR[2];

    {
        const unsigned short* Ar = A + (size_t)(m0 + arow) * K + aoff;
        #pragma unroll
        for (int c = 0; c < 4; ++c) aR[c] = *(const uint4*)(Ar + c * 8);
        const unsigned short* Wr = W + (size_t)(n0 + wrow) * K + woff;
        #pragma unroll
        for (int c = 0; c < 2; ++c) wR[c] = *(const uint4*)(Wr + c * 8);
    }

    for (int k0 = 0; k0 < K; k0 += 64) {
        __syncthreads();
        #pragma unroll
        for (int c = 0; c < 4; ++c)
            *(uint4*)&As[arow * 72 + aoff + c * 8] = aR[c];
        #pragma unroll
        for (int c = 0; c < 2; ++c)
            *(uint4*)&Ws[wrow * 72 + woff + c * 8] = wR[c];

        if (k0 + 64 < K) {
            const unsigned short* Ar = A + (size_t)(m0 + arow) * K + k0 + 64 + aoff;
            #pragma unroll
            for (int c = 0; c < 4; ++c) aR[c] = *(const uint4*)(Ar + c * 8);
            const unsigned short* Wr = W + (size_t)(n0 + wrow) * K + k0 + 64 + woff;
            #pragma unroll
            for (int c = 0; c < 2; ++c) wR[c] = *(const uint4*)(Wr + c * 8);
        }
        __syncthreads();

        #pragma unroll
        for (int ks = 0; ks < 2; ++ks) {
            bf16x8 a0 = *(bf16x8*)&As[(w * 32 + lr) * 72 + ks * 32 + lq * 8];
            bf16x8 a1 = *(bf16x8*)&As[(w * 32 + 16 + lr) * 72 + ks * 32 + lq * 8];
            #pragma unroll
            for (int j = 0; j < 4; ++j) {
                bf16x8 bb = *(bf16x8*)&Ws[(j * 16 + lr) * 72 + ks * 32 + lq * 8];
                acc[0][j] = __builtin_amdgcn_mfma_f32_16x16x32_bf16(a0, bb, acc[0][j], 0, 0, 0);
                acc[1][j] = __builtin_amdgcn_mfma_f32_16x16x32_bf16(a1, bb, acc[1][j], 0, 0, 0);
            }
        }
    }

    float cs[4] = {}, cq[4] = {};
    #pragma unroll
    for (int m = 0; m < 2; ++m)
        #pragma unroll
        for (int j = 0; j < 4; ++j)
            #pragma unroll
            for (int r = 0; r < 4; ++r) {
                float v = acc[m][j][r];
                C[(size_t)(m0 + w * 32 + m * 16 + lq * 4 + r) * 256 + n0 + j * 16 + lr] = v;
                cs[j] += v;
                cq[j] += v * v;
            }
    #pragma unroll
    for (int j = 0; j < 4; ++j) {
        cs[j] += __shfl_xor(cs[j], 16); cs[j] += __shfl_xor(cs[j], 32);
        cq[j] += __shfl_xor(cq[j], 16); cq[j] += __shfl_xor(cq[j], 32);
    }
    __syncthreads();
    float* red = (float*)As;
    if (lq == 0) {
        #pragma unroll
        for (int j = 0; j < 4; ++j) {
            red[w * 128 + j * 16 + lr]      = cs[j];
            red[w * 128 + 64 + j * 16 + lr] = cq[j];
        }
    }
    __syncthreads();
    if (tid < 128) {
        int col = tid & 63, stat = tid >> 6;
        float t = red[stat * 64 + col] + red[128 + stat * 64 + col] +
                  red[256 + stat * 64 + col] + red[384 + stat * 64 + col];
        atomicAdd((stat ? gsumsq : gsum) + n0 + col, t);
    }
}

// ---------------------------------------------------------------------------
// Normalize + affine + LeakyReLU
// ---------------------------------------------------------------------------
__global__ __launch_bounds__(256) void bn_norm4(const float* __restrict__ p,
                                                const float* __restrict__ gsum,
                                                const float* __restrict__ gsumsq,
                                                const float* __restrict__ gamma,
                                                const float* __restrict__ beta,
                                                float* __restrict__ out) {
    int i = blockIdx.x * 256 + threadIdx.x;
    int c0 = (i * 4) & 255;
    const float invN = 1.0f / (float)NROWS;
    float4 pv = *(const float4*)(p + (size_t)i * 4);
    float vals[4] = {pv.x, pv.y, pv.z, pv.w};
    float res[4];
    #pragma unroll
    for (int k = 0; k < 4; ++k) {
        int c = c0 + k;
        float mean = gsum[c] * invN;
        float var  = gsumsq[c] * invN - mean * mean;
        float v = (vals[k] - mean) * rsqrtf(var + BN_EPS) * gamma[c] + beta[c];
        res[k] = v >= 0.f ? v : NEG_SLOPE * v;
    }
    float4 ov = {res[0], res[1], res[2], res[3]};
    *(float4*)(out + (size_t)i * 4) = ov;
}

// ---------------------------------------------------------------------------
// kernel_launch
// ---------------------------------------------------------------------------
extern "C" void kernel_launch(void* const* d_in, const int* in_sizes, int n_in,
                              void* d_out, int out_size, void* d_ws, size_t ws_size,
                              hipStream_t stream) {
    const float* x     = (const float*)d_in[0];
    const float* q     = (const float*)d_in[1];
    const float* Wq    = (const float*)d_in[2];
    const float* Wk    = (const float*)d_in[3];
    const float* Wv    = (const float*)d_in[4];
    const float* Wp    = (const float*)d_in[5];
    const float* gamma = (const float*)d_in[6];
    const float* beta  = (const float*)d_in[7];
    float* out = (float*)d_out;

    char* base = (char*)d_ws;
    unsigned short* Wqb  = (unsigned short*)(base + 0);          //  512x256 bf16
    unsigned short* Wkvb = (unsigned short*)(base + 262144);     // 1024x256 bf16
    unsigned short* Wpb  = (unsigned short*)(base + 786432);     //  256x512 bf16
    unsigned short* qh   = (unsigned short*)(base + 1048576);    // 16384x512 bf16
    unsigned short* khb  = (unsigned short*)(base + 17825792);   // 16384x512 bf16
    unsigned short* vTb  = (unsigned short*)(base + 34603008);   // [16,8,64,1024] bf16
    unsigned short* ob   = (unsigned short*)(base + 51380224);   // 16384x512 bf16
    float*          pbuf = (float*)        (base + 68157440);    // 16384x256 f32
    float*          stats= (float*)        (base + 84934656);    // 512 f32

    wcast<<<512, 256, 0, stream>>>(Wq, Wk, Wv, Wp, Wqb, Wkvb, Wpb, stats);

    gemm_qkv7<<<1536, 256, 0, stream>>>(q, x, Wqb, Wkvb, qh, khb, vTb);

    attn_mfma11<<<512, 256, 0, stream>>>(qh, khb, vTb, ob);

    gemm_out<<<dim3(4, 128), 256, 0, stream>>>(ob, Wpb, pbuf, stats, stats + 256);

    bn_norm4<<<4096, 256, 0, stream>>>(pbuf, stats, stats + 256, gamma, beta, out);
}

// Round 6
// 226.980 us; speedup vs baseline: 1.1686x; 1.0711x over previous
//
#include <hip/hip_runtime.h>
#include <cstddef>

#define B_    16
#define SQ_   1024
#define SE_   1024
#define CIN_  256
#define DK_   64
#define H_    8
#define HD_   512
#define NROWS 16384
#define BN_EPS 1e-5f
#define NEG_SLOPE 0.01f

typedef __attribute__((ext_vector_type(8))) short bf16x8;
typedef __attribute__((ext_vector_type(4))) float f32x4;

// Raw barrier (no vmcnt drain) + manual LDS-write visibility wait.
// HIP __syncthreads() emits s_waitcnt vmcnt(0) lgkmcnt(0) before s_barrier,
// which drains just-issued prefetch loads -> kills software pipelining.
#define BAR()        __builtin_amdgcn_s_barrier()
#define WAIT_LGKM0() asm volatile("s_waitcnt lgkmcnt(0)" ::: "memory")

__device__ __forceinline__ unsigned short f2bf(float f) {  // RNE
    unsigned int u = __float_as_uint(f);
    return (unsigned short)((u + 0x7FFFu + ((u >> 16) & 1u)) >> 16);
}

#if __has_builtin(__builtin_amdgcn_perm)
__device__ __forceinline__ unsigned int pack_trunc(float lo, float hi) {
    return __builtin_amdgcn_perm(__float_as_uint(hi), __float_as_uint(lo), 0x07060302u);
}
#else
__device__ __forceinline__ unsigned int pack_trunc(float lo, float hi) {
    return (__float_as_uint(lo) >> 16) | (__float_as_uint(hi) & 0xFFFF0000u);
}
#endif

#if __has_builtin(__builtin_amdgcn_exp2f)
#define EXP2F(x) __builtin_amdgcn_exp2f(x)
#else
#define EXP2F(x) exp2f(x)
#endif

__device__ __forceinline__ ushort4 pack4(f32x4 v) {
    ushort4 p;
    p.x = f2bf(v[0]); p.y = f2bf(v[1]);
    p.z = f2bf(v[2]); p.w = f2bf(v[3]);
    return p;
}

// ---------------------------------------------------------------------------
// Weight casts (one dispatch). Wq gets 0.125*log2(e) folded in.
// Blocks 0..1 also zero the BN stats accumulators.
// ---------------------------------------------------------------------------
__global__ __launch_bounds__(256) void wcast(const float* __restrict__ Wq,
                                             const float* __restrict__ Wk,
                                             const float* __restrict__ Wv,
                                             const float* __restrict__ Wp,
                                             unsigned short* __restrict__ dWq,
                                             unsigned short* __restrict__ dWkv,
                                             unsigned short* __restrict__ dWp,
                                             float* __restrict__ stats) {
    if (blockIdx.x < 2) stats[blockIdx.x * 256 + threadIdx.x] = 0.f;
    int i = blockIdx.x * 256 + threadIdx.x;
    int which = i >> 15, off = i & 32767;
    const float* s; unsigned short* d; float sc = 1.0f;
    if (which == 0)      { s = Wq; d = dWq; sc = 0.18033688011112042f; }
    else if (which == 1) { s = Wk; d = dWkv; }
    else if (which == 2) { s = Wv; d = dWkv + 131072; }
    else                 { s = Wp; d = dWp; }
    float4 v = *(const float4*)(s + (size_t)off * 4);
    ushort4 pk;
    pk.x = f2bf(v.x * sc); pk.y = f2bf(v.y * sc);
    pk.z = f2bf(v.z * sc); pk.w = f2bf(v.w * sc);
    *(ushort4*)(d + (size_t)off * 4) = pk;
}

// ---------------------------------------------------------------------------
// Fused Q+KV projection GEMM v8: 128x128 tile, BK=64, register prefetch,
// XCD-aware decode (xcd=flat&7; all 12 bx-sharers of an A-panel on one XCD).
// NEW vs v7: raw-barrier k-loop. The compiler's counted vmcnt (register
// dependency of the staging ds_writes on aR/wR) replaces the __syncthreads
// vmcnt(0) drain, so next-tile prefetch loads stay in flight across the
// barrier and land during the MFMA phase.
// ---------------------------------------------------------------------------
__global__ __launch_bounds__(256) void gemm_qkv8(const float* __restrict__ qsrc,
                                                 const float* __restrict__ xsrc,
                                                 const unsigned short* __restrict__ Wqb,
                                                 const unsigned short* __restrict__ Wkvb,
                                                 unsigned short* __restrict__ qh,
                                                 unsigned short* __restrict__ khb,
                                                 unsigned short* __restrict__ vTb) {
    __shared__ __align__(16) unsigned short smem[18432];    // 36 KB
    unsigned short* As = smem;                              // 128*72
    unsigned short* Ws = smem + 9216;                       // 128*72
    unsigned short* Cs = smem;                              // epilogue: 128*144

    const int tid = threadIdx.x;
    const int w = tid >> 6, l = tid & 63, lq = l >> 4, lr = l & 15;

    // XCD-aware decode (bijective: 1536 = 8 * 192, 192 = 12 * 16)
    const int flat = blockIdx.x;
    const int xcd  = flat & 7;
    const int jj   = flat >> 3;          // 0..191
    const int bx   = jj % 12;
    const int by   = (jj / 12) + xcd * 16;

    const bool isQ = bx < 4;
    const bool isV = bx >= 8;
    const float* A = isQ ? qsrc : xsrc;
    const unsigned short* W = isQ ? Wqb : Wkvb;
    const int n0 = (isQ ? bx : bx - 4) * 128;
    const int m0 = by * 128;
    const int K = 256;

    const int srow = tid >> 1, soff = (tid & 1) * 32;   // 32 elems/thread

    f32x4 acc[2][8] = {};
    uint4 aR[8], wR[4];

    {
        const float* Ar = A + (size_t)(m0 + srow) * K + soff;
        #pragma unroll
        for (int c = 0; c < 8; ++c) aR[c] = *(const uint4*)(Ar + c * 4);
        const unsigned short* Wr = W + (size_t)(n0 + srow) * K + soff;
        #pragma unroll
        for (int c = 0; c < 4; ++c) wR[c] = *(const uint4*)(Wr + c * 8);
    }

    for (int k0 = 0; k0 < K; k0 += 64) {
        BAR();   // raw: all waves done reading prev tile (reads complete before
                 // each wave's MFMAs, which precede its barrier arrival)
        #pragma unroll
        for (int c = 0; c < 4; ++c) {
            float4 u0 = *(float4*)&aR[2 * c];
            float4 u1 = *(float4*)&aR[2 * c + 1];
            uint4 pk;
            pk.x = pack_trunc(u0.x, u0.y);
            pk.y = pack_trunc(u0.z, u0.w);
            pk.z = pack_trunc(u1.x, u1.y);
            pk.w = pack_trunc(u1.z, u1.w);
            *(uint4*)&As[srow * 72 + soff + c * 8] = pk;
            *(uint4*)&Ws[srow * 72 + soff + c * 8] = wR[c];
        }
        if (k0 + 64 < K) {       // issue next tile; stays in flight past BAR
            const float* Ar = A + (size_t)(m0 + srow) * K + k0 + 64 + soff;
            #pragma unroll
            for (int c = 0; c < 8; ++c) aR[c] = *(const uint4*)(Ar + c * 4);
            const unsigned short* Wr = W + (size_t)(n0 + srow) * K + k0 + 64 + soff;
            #pragma unroll
            for (int c = 0; c < 4; ++c) wR[c] = *(const uint4*)(Wr + c * 8);
        }
        WAIT_LGKM0();            // my LDS writes committed
        BAR();                   // all writes visible; vmcnt NOT drained

        if (!isV) {   // transposed compute: D[n][m]
            #pragma unroll
            for (int ks = 0; ks < 2; ++ks) {
                bf16x8 a0 = *(bf16x8*)&As[(w * 32 + lr) * 72 + ks * 32 + lq * 8];
                bf16x8 a1 = *(bf16x8*)&As[(w * 32 + 16 + lr) * 72 + ks * 32 + lq * 8];
                #pragma unroll
                for (int j = 0; j < 8; ++j) {
                    bf16x8 bb = *(bf16x8*)&Ws[(j * 16 + lr) * 72 + ks * 32 + lq * 8];
                    acc[0][j] = __builtin_amdgcn_mfma_f32_16x16x32_bf16(bb, a0, acc[0][j], 0, 0, 0);
                    acc[1][j] = __builtin_amdgcn_mfma_f32_16x16x32_bf16(bb, a1, acc[1][j], 0, 0, 0);
                }
            }
        } else {      // normal compute: D[m][n]
            #pragma unroll
            for (int ks = 0; ks < 2; ++ks) {
                bf16x8 a0 = *(bf16x8*)&As[(w * 32 + lr) * 72 + ks * 32 + lq * 8];
                bf16x8 a1 = *(bf16x8*)&As[(w * 32 + 16 + lr) * 72 + ks * 32 + lq * 8];
                #pragma unroll
                for (int j = 0; j < 8; ++j) {
                    bf16x8 bb = *(bf16x8*)&Ws[(j * 16 + lr) * 72 + ks * 32 + lq * 8];
                    acc[0][j] = __builtin_amdgcn_mfma_f32_16x16x32_bf16(a0, bb, acc[0][j], 0, 0, 0);
                    acc[1][j] = __builtin_amdgcn_mfma_f32_16x16x32_bf16(a1, bb, acc[1][j], 0, 0, 0);
                }
            }
        }
    }

    // ---- Epilogue: LDS staging, then full-line coalesced stores ----
    __syncthreads();   // full drain fine: once per block, no prefetch pending
    const int c16 = tid & 15;
    const int rb  = tid >> 4;
    if (!isV) {
        #pragma unroll
        for (int mf = 0; mf < 2; ++mf)
            #pragma unroll
            for (int j = 0; j < 8; ++j)
                *(ushort4*)&Cs[(w * 32 + mf * 16 + lr) * 144 + j * 16 + lq * 4] =
                    pack4(acc[mf][j]);
        __syncthreads();
        unsigned short* C = isQ ? qh : khb;
        #pragma unroll
        for (int it = 0; it < 8; ++it) {
            int r = it * 16 + rb;
            *(uint4*)(C + (size_t)(m0 + r) * 512 + n0 + c16 * 8) =
                *(const uint4*)(Cs + r * 144 + c16 * 8);
        }
    } else {
        #pragma unroll
        for (int mf = 0; mf < 2; ++mf)
            #pragma unroll
            for (int j = 0; j < 8; ++j)
                *(ushort4*)&Cs[(j * 16 + lr) * 144 + w * 32 + mf * 16 + lq * 4] =
                    pack4(acc[mf][j]);
        __syncthreads();
        const int bb = m0 >> 10, t0 = m0 & 1023;
        #pragma unroll
        for (int it = 0; it < 8; ++it) {
            int el = it * 16 + rb;
            int colv = n0 - 512 + el;
            int hh = colv >> 6, e = colv & 63;
            *(uint4*)(vTb + (size_t)((bb * 8 + hh) * 64 + e) * 1024 + t0 + c16 * 8) =
                *(const uint4*)(Cs + el * 144 + c16 * 8);
        }
    }
}

// ---------------------------------------------------------------------------
// MFMA flash attention v12: v11 (half-split pipeline + XCD decode) with
// raw-barrier staging: K/V prefetch issued for tile t+1 now survives the
// post-staging barrier (previously __syncthreads drained it synchronously).
// ---------------------------------------------------------------------------
__global__ __launch_bounds__(256) void attn_mfma12(const unsigned short* __restrict__ qh,
                                                   const unsigned short* __restrict__ kh,
                                                   const unsigned short* __restrict__ vT,
                                                   unsigned short* __restrict__ o) {
    __shared__ __align__(16) unsigned short Ks[64 * 64];      // swizzled  8 KB
    __shared__ __align__(16) unsigned short Vs[64 * 64];      // swizzled  8 KB
    __shared__ __align__(16) unsigned short Ps[4][64 * 40];   // per-wave 20 KB

    const int tid = threadIdx.x;
    const int w = tid >> 6, l = tid & 63, lq = l >> 4, lr = l & 15;

    // XCD-aware decode (bijective: 512 = 8 * 64, 64 = 4 * 16)
    const int flat = blockIdx.x;
    const int xcd  = flat & 7;
    const int jj   = flat >> 3;          // 0..63
    const int q0   = (jj & 3) * 256;
    const int hb   = (jj >> 2) + xcd * 16;   // 0..127
    const int h    = hb & 7;
    const int b    = hb >> 3;

    const int swz = (lr & 7) << 3;            // XOR swizzle for K/V reads (shorts)

    // Q fragments: lane lr holds row m = mm*16+lr, elems k = lq*8+j (+32)
    bf16x8 qf[4][2];
    #pragma unroll
    for (int mm = 0; mm < 4; ++mm) {
        const unsigned short* qr =
            qh + (size_t)(b * SQ_ + q0 + w * 64 + mm * 16 + lr) * HD_ + h * DK_;
        qf[mm][0] = *(const bf16x8*)(qr + lq * 8);
        qf[mm][1] = *(const bf16x8*)(qr + 32 + lq * 8);
    }

    const unsigned short* kb = kh + (size_t)(b * SE_) * HD_ + h * DK_;
    const unsigned short* vb = vT + (size_t)((b * 8 + h) * 64) * 1024;

    const int se = tid >> 3;                  // 0..31
    const int sc = (tid & 7) * 8;
    const int sswz = (se & 7) << 3;           // staging-write swizzle (rr&7 == se&7)

    float l_i[4] = {};                        // per-lane partial row-sum
    f32x4 oacc[4][4] = {};                    // [mm][e-strip j]; D[e][m]
    unsigned short* Pw = Ps[w];

    // ---- prefetch K/V tile 0 into registers ----
    uint4 kR[2], vR[2];
    #pragma unroll
    for (int ps = 0; ps < 2; ++ps) {
        int rr = se + ps * 32;
        kR[ps] = *(const uint4*)(kb + (size_t)rr * HD_ + sc);
        vR[ps] = *(const uint4*)(vb + (size_t)rr * 1024 + sc);
    }

    for (int t0 = 0; t0 < SE_; t0 += 64) {
        BAR();   // raw: all waves done reading Ks/Vs of prev tile
        // write current tile (compiler inserts counted vmcnt for kR/vR deps)
        #pragma unroll
        for (int ps = 0; ps < 2; ++ps) {
            int rr = se + ps * 32;
            int ad = ((rr * 64 + sc) ^ sswz);
            *(uint4*)&Ks[ad] = kR[ps];
            *(uint4*)&Vs[ad] = vR[ps];
        }
        // issue next tile's loads; they stay in flight across the barrier
        if (t0 + 64 < SE_) {
            #pragma unroll
            for (int ps = 0; ps < 2; ++ps) {
                int rr = se + ps * 32;
                kR[ps] = *(const uint4*)(kb + (size_t)(t0 + 64 + rr) * HD_ + sc);
                vR[ps] = *(const uint4*)(vb + (size_t)rr * 1024 + t0 + 64 + sc);
            }
        }
        WAIT_LGKM0();            // my Ks/Vs writes committed
        BAR();                   // all writes visible; vmcnt NOT drained

        // ---- QK^T half 0: keys t0..t0+31 ----
        f32x4 s0[2][4] = {};
        __builtin_amdgcn_s_setprio(1);
        #pragma unroll
        for (int ks = 0; ks < 2; ++ks)
            #pragma unroll
            for (int tt = 0; tt < 2; ++tt) {
                bf16x8 kf = *(bf16x8*)&Ks[((tt * 16 + lr) * 64 + ks * 32 + lq * 8) ^ swz];
                #pragma unroll
                for (int mm = 0; mm < 4; ++mm)
                    s0[tt][mm] = __builtin_amdgcn_mfma_f32_16x16x32_bf16(kf, qf[mm][ks], s0[tt][mm], 0, 0, 0);
            }
        __builtin_amdgcn_s_setprio(0);

        // exp0 + P0 write (t-local cols 0..31)
        #pragma unroll
        for (int mm = 0; mm < 4; ++mm)
            #pragma unroll
            for (int tt = 0; tt < 2; ++tt) {
                float e0 = EXP2F(s0[tt][mm][0]);
                float e1 = EXP2F(s0[tt][mm][1]);
                float e2 = EXP2F(s0[tt][mm][2]);
                float e3 = EXP2F(s0[tt][mm][3]);
                l_i[mm] += (e0 + e1) + (e2 + e3);
                uint2 pk;
                pk.x = pack_trunc(e0, e1);
                pk.y = pack_trunc(e2, e3);
                *(uint2*)&Pw[(mm * 16 + lr) * 40 + tt * 16 + lq * 4] = pk;
            }

        // ---- QK^T half 1: keys t0+32..t0+63 (overlaps P0 write latency) ----
        f32x4 s1[2][4] = {};
        __builtin_amdgcn_s_setprio(1);
        #pragma unroll
        for (int ks = 0; ks < 2; ++ks)
            #pragma unroll
            for (int tt = 0; tt < 2; ++tt) {
                bf16x8 kf = *(bf16x8*)&Ks[(((tt + 2) * 16 + lr) * 64 + ks * 32 + lq * 8) ^ swz];
                #pragma unroll
                for (int mm = 0; mm < 4; ++mm)
                    s1[tt][mm] = __builtin_amdgcn_mfma_f32_16x16x32_bf16(kf, qf[mm][ks], s1[tt][mm], 0, 0, 0);
            }
        __builtin_amdgcn_s_setprio(0);

        asm volatile("s_waitcnt lgkmcnt(0)" ::: "memory");   // P0 writes done

        // ---- PV half 0: V cols t0..t0+31 (MFMAs overlap exp1 below) ----
        __builtin_amdgcn_s_setprio(1);
        {
            bf16x8 pf[4];
            #pragma unroll
            for (int mm = 0; mm < 4; ++mm)
                pf[mm] = *(bf16x8*)&Pw[(mm * 16 + lr) * 40 + lq * 8];
            #pragma unroll
            for (int j = 0; j < 4; ++j) {
                bf16x8 vf = *(bf16x8*)&Vs[((j * 16 + lr) * 64 + lq * 8) ^ swz];
                #pragma unroll
                for (int mm = 0; mm < 4; ++mm)
                    oacc[mm][j] = __builtin_amdgcn_mfma_f32_16x16x32_bf16(vf, pf[mm], oacc[mm][j], 0, 0, 0);
            }
        }
        __builtin_amdgcn_s_setprio(0);

        // exp1 + P1 write (reuses P slots; WAR-safe: PV(h0) reads issued first)
        #pragma unroll
        for (int mm = 0; mm < 4; ++mm)
            #pragma unroll
            for (int tt = 0; tt < 2; ++tt) {
                float e0 = EXP2F(s1[tt][mm][0]);
                float e1 = EXP2F(s1[tt][mm][1]);
                float e2 = EXP2F(s1[tt][mm][2]);
                float e3 = EXP2F(s1[tt][mm][3]);
                l_i[mm] += (e0 + e1) + (e2 + e3);
                uint2 pk;
                pk.x = pack_trunc(e0, e1);
                pk.y = pack_trunc(e2, e3);
                *(uint2*)&Pw[(mm * 16 + lr) * 40 + tt * 16 + lq * 4] = pk;
            }

        asm volatile("s_waitcnt lgkmcnt(0)" ::: "memory");   // P1 writes done

        // ---- PV half 1: V cols t0+32..t0+63 ----
        __builtin_amdgcn_s_setprio(1);
        {
            bf16x8 pf[4];
            #pragma unroll
            for (int mm = 0; mm < 4; ++mm)
                pf[mm] = *(bf16x8*)&Pw[(mm * 16 + lr) * 40 + lq * 8];
            #pragma unroll
            for (int j = 0; j < 4; ++j) {
                bf16x8 vf = *(bf16x8*)&Vs[((j * 16 + lr) * 64 + 32 + lq * 8) ^ swz];
                #pragma unroll
                for (int mm = 0; mm < 4; ++mm)
                    oacc[mm][j] = __builtin_amdgcn_mfma_f32_16x16x32_bf16(vf, pf[mm], oacc[mm][j], 0, 0, 0);
            }
        }
        __builtin_amdgcn_s_setprio(0);
    }

    float inv[4];
    #pragma unroll
    for (int mm = 0; mm < 4; ++mm) {
        float t = l_i[mm];
        t += __shfl_xor(t, 16);
        t += __shfl_xor(t, 32);
        inv[mm] = 1.0f / t;
    }

    // o store: D row = e_local = lq*4+r (4 consecutive e), col = m = lr.
    #pragma unroll
    for (int mm = 0; mm < 4; ++mm)
        #pragma unroll
        for (int j = 0; j < 4; ++j) {
            f32x4 v = oacc[mm][j];
            v[0] *= inv[mm]; v[1] *= inv[mm]; v[2] *= inv[mm]; v[3] *= inv[mm];
            *(ushort4*)&o[(size_t)(b * SQ_ + q0 + w * 64 + mm * 16 + lr) * HD_ +
                          h * DK_ + j * 16 + lq * 4] = pack4(v);
        }
}

// ---------------------------------------------------------------------------
// Output projection v2: p = o @ Wp^T (bf16 in, f32 out) + fused BN partials.
// 128x64 tiles, K=512, register prefetch, raw-barrier k-loop (same fix).
// ---------------------------------------------------------------------------
__global__ __launch_bounds__(256) void gemm_out2(const unsigned short* __restrict__ A,
                                                 const unsigned short* __restrict__ W,
                                                 float* __restrict__ C,
                                                 float* __restrict__ gsum,
                                                 float* __restrict__ gsumsq) {
    __shared__ __align__(16) unsigned short As[128 * 72];
    __shared__ __align__(16) unsigned short Ws[64 * 72];
    const int tid = threadIdx.x;
    const int w = tid >> 6, l = tid & 63, lq = l >> 4, lr = l & 15;
    const int n0 = blockIdx.x * 64, m0 = blockIdx.y * 128;
    const int K = 512;

    const int arow = tid >> 1, aoff = (tid & 1) * 32;
    const int wrow = tid >> 2, woff = (tid & 3) * 16;

    f32x4 acc[2][4] = {};
    uint4 aR[4], wR[2];

    {
        const unsigned short* Ar = A + (size_t)(m0 + arow) * K + aoff;
        #pragma unroll
        for (int c = 0; c < 4; ++c) aR[c] = *(const uint4*)(Ar + c * 8);
        const unsigned short* Wr = W + (size_t)(n0 + wrow) * K + woff;
        #pragma unroll
        for (int c = 0; c < 2; ++c) wR[c] = *(const uint4*)(Wr + c * 8);
    }

    for (int k0 = 0; k0 < K; k0 += 64) {
        BAR();
        #pragma unroll
        for (int c = 0; c < 4; ++c)
            *(uint4*)&As[arow * 72 + aoff + c * 8] = aR[c];
        #pragma unroll
        for (int c = 0; c < 2; ++c)
            *(uint4*)&Ws[wrow * 72 + woff + c * 8] = wR[c];

        if (k0 + 64 < K) {
            const unsigned short* Ar = A + (size_t)(m0 + arow) * K + k0 + 64 + aoff;
            #pragma unroll
            for (int c = 0; c < 4; ++c) aR[c] = *(const uint4*)(Ar + c * 8);
            const unsigned short* Wr = W + (size_t)(n0 + wrow) * K + k0 + 64 + woff;
            #pragma unroll
            for (int c = 0; c < 2; ++c) wR[c] = *(const uint4*)(Wr + c * 8);
        }
        WAIT_LGKM0();
        BAR();

        #pragma unroll
        for (int ks = 0; ks < 2; ++ks) {
            bf16x8 a0 = *(bf16x8*)&As[(w * 32 + lr) * 72 + ks * 32 + lq * 8];
            bf16x8 a1 = *(bf16x8*)&As[(w * 32 + 16 + lr) * 72 + ks * 32 + lq * 8];
            #pragma unroll
            for (int j = 0; j < 4; ++j) {
                bf16x8 bb = *(bf16x8*)&Ws[(j * 16 + lr) * 72 + ks * 32 + lq * 8];
                acc[0][j] = __builtin_amdgcn_mfma_f32_16x16x32_bf16(a0, bb, acc[0][j], 0, 0, 0);
                acc[1][j] = __builtin_amdgcn_mfma_f32_16x16x32_bf16(a1, bb, acc[1][j], 0, 0, 0);
            }
        }
    }

    float cs[4] = {}, cq[4] = {};
    #pragma unroll
    for (int m = 0; m < 2; ++m)
        #pragma unroll
        for (int j = 0; j < 4; ++j)
            #pragma unroll
            for (int r = 0; r < 4; ++r) {
                float v = acc[m][j][r];
                C[(size_t)(m0 + w * 32 + m * 16 + lq * 4 + r) * 256 + n0 + j * 16 + lr] = v;
                cs[j] += v;
                cq[j] += v * v;
            }
    #pragma unroll
    for (int j = 0; j < 4; ++j) {
        cs[j] += __shfl_xor(cs[j], 16); cs[j] += __shfl_xor(cs[j], 32);
        cq[j] += __shfl_xor(cq[j], 16); cq[j] += __shfl_xor(cq[j], 32);
    }
    __syncthreads();
    float* red = (float*)As;
    if (lq == 0) {
        #pragma unroll
        for (int j = 0; j < 4; ++j) {
            red[w * 128 + j * 16 + lr]      = cs[j];
            red[w * 128 + 64 + j * 16 + lr] = cq[j];
        }
    }
    __syncthreads();
    if (tid < 128) {
        int col = tid & 63, stat = tid >> 6;
        float t = red[stat * 64 + col] + red[128 + stat * 64 + col] +
                  red[256 + stat * 64 + col] + red[384 + stat * 64 + col];
        atomicAdd((stat ? gsumsq : gsum) + n0 + col, t);
    }
}

// ---------------------------------------------------------------------------
// Normalize + affine + LeakyReLU
// ---------------------------------------------------------------------------
__global__ __launch_bounds__(256) void bn_norm4(const float* __restrict__ p,
                                                const float* __restrict__ gsum,
                                                const float* __restrict__ gsumsq,
                                                const float* __restrict__ gamma,
                                                const float* __restrict__ beta,
                                                float* __restrict__ out) {
    int i = blockIdx.x * 256 + threadIdx.x;
    int c0 = (i * 4) & 255;
    const float invN = 1.0f / (float)NROWS;
    float4 pv = *(const float4*)(p + (size_t)i * 4);
    float vals[4] = {pv.x, pv.y, pv.z, pv.w};
    float res[4];
    #pragma unroll
    for (int k = 0; k < 4; ++k) {
        int c = c0 + k;
        float mean = gsum[c] * invN;
        float var  = gsumsq[c] * invN - mean * mean;
        float v = (vals[k] - mean) * rsqrtf(var + BN_EPS) * gamma[c] + beta[c];
        res[k] = v >= 0.f ? v : NEG_SLOPE * v;
    }
    float4 ov = {res[0], res[1], res[2], res[3]};
    *(float4*)(out + (size_t)i * 4) = ov;
}

// ---------------------------------------------------------------------------
// kernel_launch
// ---------------------------------------------------------------------------
extern "C" void kernel_launch(void* const* d_in, const int* in_sizes, int n_in,
                              void* d_out, int out_size, void* d_ws, size_t ws_size,
                              hipStream_t stream) {
    const float* x     = (const float*)d_in[0];
    const float* q     = (const float*)d_in[1];
    const float* Wq    = (const float*)d_in[2];
    const float* Wk    = (const float*)d_in[3];
    const float* Wv    = (const float*)d_in[4];
    const float* Wp    = (const float*)d_in[5];
    const float* gamma = (const float*)d_in[6];
    const float* beta  = (const float*)d_in[7];
    float* out = (float*)d_out;

    char* base = (char*)d_ws;
    unsigned short* Wqb  = (unsigned short*)(base + 0);          //  512x256 bf16
    unsigned short* Wkvb = (unsigned short*)(base + 262144);     // 1024x256 bf16
    unsigned short* Wpb  = (unsigned short*)(base + 786432);     //  256x512 bf16
    unsigned short* qh   = (unsigned short*)(base + 1048576);    // 16384x512 bf16
    unsigned short* khb  = (unsigned short*)(base + 17825792);   // 16384x512 bf16
    unsigned short* vTb  = (unsigned short*)(base + 34603008);   // [16,8,64,1024] bf16
    unsigned short* ob   = (unsigned short*)(base + 51380224);   // 16384x512 bf16
    float*          pbuf = (float*)        (base + 68157440);    // 16384x256 f32
    float*          stats= (float*)        (base + 84934656);    // 512 f32

    wcast<<<512, 256, 0, stream>>>(Wq, Wk, Wv, Wp, Wqb, Wkvb, Wpb, stats);

    gemm_qkv8<<<1536, 256, 0, stream>>>(q, x, Wqb, Wkvb, qh, khb, vTb);

    attn_mfma12<<<512, 256, 0, stream>>>(qh, khb, vTb, ob);

    gemm_out2<<<dim3(4, 128), 256, 0, stream>>>(ob, Wpb, pbuf, stats, stats + 256);

    bn_norm4<<<4096, 256, 0, stream>>>(pbuf, stats, stats + 256, gamma, beta, out);
}

// Round 8
// 224.371 us; speedup vs baseline: 1.1822x; 1.0116x over previous
//
#include <hip/hip_runtime.h>
#include <cstddef>

#define B_    16
#define SQ_   1024
#define SE_   1024
#define CIN_  256
#define DK_   64
#define H_    8
#define HD_   512
#define NROWS 16384
#define BN_EPS 1e-5f
#define NEG_SLOPE 0.01f

typedef __attribute__((ext_vector_type(8))) short bf16x8;
typedef __attribute__((ext_vector_type(4))) float f32x4;

// Raw barrier (no vmcnt drain) + manual LDS-write visibility wait.
#define BAR()        __builtin_amdgcn_s_barrier()
#define WAIT_LGKM0() asm volatile("s_waitcnt lgkmcnt(0)" ::: "memory")

__device__ __forceinline__ unsigned short f2bf(float f) {  // RNE
    unsigned int u = __float_as_uint(f);
    return (unsigned short)((u + 0x7FFFu + ((u >> 16) & 1u)) >> 16);
}

#if __has_builtin(__builtin_amdgcn_perm)
__device__ __forceinline__ unsigned int pack_trunc(float lo, float hi) {
    return __builtin_amdgcn_perm(__float_as_uint(hi), __float_as_uint(lo), 0x07060302u);
}
#else
__device__ __forceinline__ unsigned int pack_trunc(float lo, float hi) {
    return (__float_as_uint(lo) >> 16) | (__float_as_uint(hi) & 0xFFFF0000u);
}
#endif

#if __has_builtin(__builtin_amdgcn_exp2f)
#define EXP2F(x) __builtin_amdgcn_exp2f(x)
#else
#define EXP2F(x) exp2f(x)
#endif

__device__ __forceinline__ ushort4 pack4(f32x4 v) {
    ushort4 p;
    p.x = f2bf(v[0]); p.y = f2bf(v[1]);
    p.z = f2bf(v[2]); p.w = f2bf(v[3]);
    return p;
}

__device__ __forceinline__ bf16x8 cvt8(float4 f0, float4 f1) {  // trunc f32->bf16 x8
    uint4 pk;
    pk.x = pack_trunc(f0.x, f0.y);
    pk.y = pack_trunc(f0.z, f0.w);
    pk.z = pack_trunc(f1.x, f1.y);
    pk.w = pack_trunc(f1.z, f1.w);
    return *(bf16x8*)&pk;
}

// ---------------------------------------------------------------------------
// Weight casts (one dispatch). Wq gets 0.125*log2(e) folded in.
// Blocks 0..1 also zero the BN stats accumulators.
// ---------------------------------------------------------------------------
__global__ __launch_bounds__(256) void wcast(const float* __restrict__ Wq,
                                             const float* __restrict__ Wk,
                                             const float* __restrict__ Wv,
                                             const float* __restrict__ Wp,
                                             unsigned short* __restrict__ dWq,
                                             unsigned short* __restrict__ dWkv,
                                             unsigned short* __restrict__ dWp,
                                             float* __restrict__ stats) {
    if (blockIdx.x < 2) stats[blockIdx.x * 256 + threadIdx.x] = 0.f;
    int i = blockIdx.x * 256 + threadIdx.x;
    int which = i >> 15, off = i & 32767;
    const float* s; unsigned short* d; float sc = 1.0f;
    if (which == 0)      { s = Wq; d = dWq; sc = 0.18033688011112042f; }
    else if (which == 1) { s = Wk; d = dWkv; }
    else if (which == 2) { s = Wv; d = dWkv + 131072; }
    else                 { s = Wp; d = dWp; }
    float4 v = *(const float4*)(s + (size_t)off * 4);
    ushort4 pk;
    pk.x = f2bf(v.x * sc); pk.y = f2bf(v.y * sc);
    pk.z = f2bf(v.z * sc); pk.w = f2bf(v.w * sc);
    *(ushort4*)(d + (size_t)off * 4) = pk;
}

// ---------------------------------------------------------------------------
// Fused Q+KV projection GEMM v9: BARRIER-FREE k-loop.
// W tile (128x256 bf16 = 64 KB) staged in LDS ONCE (XOR-swizzled,
// colu^(row&7) in 16B units); each wave loads its OWN A rows (w*32..+31,
// exclusively owned -> LDS staging of A was pure overhead) directly from
// global f32, converts in-register, double-buffered 2 k-steps deep.
// Zero barriers in the k-loop: 8 waves/CU free-run, latency self-hides.
// XCD-aware decode kept (A panels + W all L2-resident per XCD).
// ---------------------------------------------------------------------------
__global__ __launch_bounds__(256) void gemm_qkv9(const float* __restrict__ qsrc,
                                                 const float* __restrict__ xsrc,
                                                 const unsigned short* __restrict__ Wqb,
                                                 const unsigned short* __restrict__ Wkvb,
                                                 unsigned short* __restrict__ qh,
                                                 unsigned short* __restrict__ khb,
                                                 unsigned short* __restrict__ vTb) {
    __shared__ __align__(16) unsigned short smem[32768];    // 64 KB
    unsigned short* Ws = smem;                              // W tile, swizzled
    unsigned short* Cs = smem;                              // epilogue reuse

    const int tid = threadIdx.x;
    const int w = tid >> 6, l = tid & 63, lq = l >> 4, lr = l & 15;

    // XCD-aware decode (bijective: 1536 = 8 * 192, 192 = 12 * 16)
    const int flat = blockIdx.x;
    const int xcd  = flat & 7;
    const int jj   = flat >> 3;          // 0..191
    const int bx   = jj % 12;
    const int by   = (jj / 12) + xcd * 16;

    const bool isQ = bx < 4;
    const bool isV = bx >= 8;
    const float* A = isQ ? qsrc : xsrc;
    const unsigned short* W = isQ ? Wqb : Wkvb;
    const int n0 = (isQ ? bx : bx - 4) * 128;
    const int m0 = by * 128;

    f32x4 acc[2][8] = {};
    float4 aA[8], aB[8];

    // per-wave A row bases (wave w owns rows w*32 .. w*32+31)
    const float* A0 = A + (size_t)(m0 + w * 32 + lr) * 256 + lq * 8;        // m=0
    const float* A1 = A + (size_t)(m0 + w * 32 + 16 + lr) * 256 + lq * 8;   // m=1

#define LOAD_A(buf, kstep) do {                                              \
        buf[0] = *(const float4*)(A0 + (kstep) * 64);                        \
        buf[1] = *(const float4*)(A0 + (kstep) * 64 + 4);                    \
        buf[2] = *(const float4*)(A0 + (kstep) * 64 + 32);                   \
        buf[3] = *(const float4*)(A0 + (kstep) * 64 + 36);                   \
        buf[4] = *(const float4*)(A1 + (kstep) * 64);                        \
        buf[5] = *(const float4*)(A1 + (kstep) * 64 + 4);                    \
        buf[6] = *(const float4*)(A1 + (kstep) * 64 + 32);                   \
        buf[7] = *(const float4*)(A1 + (kstep) * 64 + 36);                   \
    } while (0)

#define QKV_STEP(buf, kstep) do {                                            \
        _Pragma("unroll")                                                    \
        for (int ks = 0; ks < 2; ++ks) {                                     \
            bf16x8 a0 = cvt8(buf[ks * 2], buf[ks * 2 + 1]);                  \
            bf16x8 a1 = cvt8(buf[4 + ks * 2], buf[4 + ks * 2 + 1]);          \
            const int colu = (kstep) * 8 + ks * 4 + lq;                      \
            const int cswz = colu ^ (lr & 7);                                \
            if (!isV) {                                                      \
                _Pragma("unroll")                                            \
                for (int j = 0; j < 8; ++j) {                                \
                    bf16x8 bb = *(bf16x8*)&Ws[((j * 16 + lr) * 32 + cswz) * 8]; \
                    acc[0][j] = __builtin_amdgcn_mfma_f32_16x16x32_bf16(bb, a0, acc[0][j], 0, 0, 0); \
                    acc[1][j] = __builtin_amdgcn_mfma_f32_16x16x32_bf16(bb, a1, acc[1][j], 0, 0, 0); \
                }                                                            \
            } else {                                                         \
                _Pragma("unroll")                                            \
                for (int j = 0; j < 8; ++j) {                                \
                    bf16x8 bb = *(bf16x8*)&Ws[((j * 16 + lr) * 32 + cswz) * 8]; \
                    acc[0][j] = __builtin_amdgcn_mfma_f32_16x16x32_bf16(a0, bb, acc[0][j], 0, 0, 0); \
                    acc[1][j] = __builtin_amdgcn_mfma_f32_16x16x32_bf16(a1, bb, acc[1][j], 0, 0, 0); \
                }                                                            \
            }                                                                \
        }                                                                    \
    } while (0)

    // step-0 A loads overlap the W staging latency
    LOAD_A(aA, 0);

    // ---- stage W once: 128 rows x 32 16B-units, swizzled colu^(row&7) ----
    #pragma unroll
    for (int i = 0; i < 16; ++i) {
        int u = tid + i * 256;                 // 0..4095
        int row = u >> 5, colu = u & 31;
        uint4 v = *(const uint4*)(W + (size_t)(n0 + row) * 256 + colu * 8);
        *(uint4*)&Ws[(row * 32 + (colu ^ (row & 7))) * 8] = v;
    }
    __syncthreads();   // once per block; no pipelined loads to protect yet

    LOAD_A(aB, 1);
    QKV_STEP(aA, 0);
    LOAD_A(aA, 2);
    QKV_STEP(aB, 1);
    LOAD_A(aB, 3);
    QKV_STEP(aA, 2);
    QKV_STEP(aB, 3);

#undef LOAD_A
#undef QKV_STEP

    // ---- Epilogue: LDS staging, then full-line coalesced stores ----
    __syncthreads();
    const int c16 = tid & 15;
    const int rb  = tid >> 4;
    if (!isV) {
        #pragma unroll
        for (int mf = 0; mf < 2; ++mf)
            #pragma unroll
            for (int j = 0; j < 8; ++j)
                *(ushort4*)&Cs[(w * 32 + mf * 16 + lr) * 144 + j * 16 + lq * 4] =
                    pack4(acc[mf][j]);
        __syncthreads();
        unsigned short* C = isQ ? qh : khb;
        #pragma unroll
        for (int it = 0; it < 8; ++it) {
            int r = it * 16 + rb;
            *(uint4*)(C + (size_t)(m0 + r) * 512 + n0 + c16 * 8) =
                *(const uint4*)(Cs + r * 144 + c16 * 8);
        }
    } else {
        #pragma unroll
        for (int mf = 0; mf < 2; ++mf)
            #pragma unroll
            for (int j = 0; j < 8; ++j)
                *(ushort4*)&Cs[(j * 16 + lr) * 144 + w * 32 + mf * 16 + lq * 4] =
                    pack4(acc[mf][j]);
        __syncthreads();
        const int bb = m0 >> 10, t0 = m0 & 1023;
        #pragma unroll
        for (int it = 0; it < 8; ++it) {
            int el = it * 16 + rb;
            int colv = n0 - 512 + el;
            int hh = colv >> 6, e = colv & 63;
            *(uint4*)(vTb + (size_t)((bb * 8 + hh) * 64 + e) * 1024 + t0 + c16 * 8) =
                *(const uint4*)(Cs + el * 144 + c16 * 8);
        }
    }
}

// ---------------------------------------------------------------------------
// MFMA flash attention v13: occupancy x2. 1024 blocks x 128 q-rows
// (32 q-rows/wave, mm=0..1). LDS 26.2 KB -> 4 blocks/CU resident
// (16 waves/CU vs 8): cross-block TLP hides the per-tile latency the
// half-split pipeline can't. Same raw-barrier staging + half-split
// QK/softmax/PV overlap as v12.
// ---------------------------------------------------------------------------
__global__ __launch_bounds__(256) void attn_mfma13(const unsigned short* __restrict__ qh,
                                                   const unsigned short* __restrict__ kh,
                                                   const unsigned short* __restrict__ vT,
                                                   unsigned short* __restrict__ o) {
    __shared__ __align__(16) unsigned short Ks[64 * 64];      // swizzled  8 KB
    __shared__ __align__(16) unsigned short Vs[64 * 64];      // swizzled  8 KB
    __shared__ __align__(16) unsigned short Ps[4][32 * 40];   // per-wave 10.2 KB

    const int tid = threadIdx.x;
    const int w = tid >> 6, l = tid & 63, lq = l >> 4, lr = l & 15;

    // XCD-aware decode (bijective: 1024 = 8 * 128, 128 = 8 q-chunks * 16 hb)
    const int flat = blockIdx.x;
    const int xcd  = flat & 7;
    const int jj   = flat >> 3;              // 0..127
    const int q0   = (jj & 7) * 128;
    const int hb   = (jj >> 3) + xcd * 16;   // 0..127
    const int h    = hb & 7;
    const int b    = hb >> 3;

    const int swz = (lr & 7) << 3;            // XOR swizzle for K/V reads (shorts)

    // Q fragments: lane lr holds row m = mm*16+lr (mm 0..1)
    bf16x8 qf[2][2];
    #pragma unroll
    for (int mm = 0; mm < 2; ++mm) {
        const unsigned short* qr =
            qh + (size_t)(b * SQ_ + q0 + w * 32 + mm * 16 + lr) * HD_ + h * DK_;
        qf[mm][0] = *(const bf16x8*)(qr + lq * 8);
        qf[mm][1] = *(const bf16x8*)(qr + 32 + lq * 8);
    }

    const unsigned short* kb = kh + (size_t)(b * SE_) * HD_ + h * DK_;
    const unsigned short* vb = vT + (size_t)((b * 8 + h) * 64) * 1024;

    const int se = tid >> 3;                  // 0..31
    const int sc = (tid & 7) * 8;
    const int sswz = (se & 7) << 3;           // staging-write swizzle (rr&7 == se&7)

    float l_i[2] = {};                        // per-lane partial row-sum
    f32x4 oacc[2][4] = {};                    // [mm][e-strip j]; D[e][m]
    unsigned short* Pw = Ps[w];

    // ---- prefetch K/V tile 0 into registers ----
    uint4 kR[2], vR[2];
    #pragma unroll
    for (int ps = 0; ps < 2; ++ps) {
        int rr = se + ps * 32;
        kR[ps] = *(const uint4*)(kb + (size_t)rr * HD_ + sc);
        vR[ps] = *(const uint4*)(vb + (size_t)rr * 1024 + sc);
    }

    for (int t0 = 0; t0 < SE_; t0 += 64) {
        BAR();   // raw: all waves done reading Ks/Vs of prev tile
        #pragma unroll
        for (int ps = 0; ps < 2; ++ps) {
            int rr = se + ps * 32;
            int ad = ((rr * 64 + sc) ^ sswz);
            *(uint4*)&Ks[ad] = kR[ps];
            *(uint4*)&Vs[ad] = vR[ps];
        }
        // issue next tile's loads; they stay in flight across the barrier
        if (t0 + 64 < SE_) {
            #pragma unroll
            for (int ps = 0; ps < 2; ++ps) {
                int rr = se + ps * 32;
                kR[ps] = *(const uint4*)(kb + (size_t)(t0 + 64 + rr) * HD_ + sc);
                vR[ps] = *(const uint4*)(vb + (size_t)rr * 1024 + t0 + 64 + sc);
            }
        }
        WAIT_LGKM0();            // my Ks/Vs writes committed
        BAR();                   // all writes visible; vmcnt NOT drained

        // ---- QK^T half 0: keys t0..t0+31 ----
        f32x4 s0[2][2] = {};
        __builtin_amdgcn_s_setprio(1);
        #pragma unroll
        for (int ks = 0; ks < 2; ++ks)
            #pragma unroll
            for (int tt = 0; tt < 2; ++tt) {
                bf16x8 kf = *(bf16x8*)&Ks[((tt * 16 + lr) * 64 + ks * 32 + lq * 8) ^ swz];
                #pragma unroll
                for (int mm = 0; mm < 2; ++mm)
                    s0[tt][mm] = __builtin_amdgcn_mfma_f32_16x16x32_bf16(kf, qf[mm][ks], s0[tt][mm], 0, 0, 0);
            }
        __builtin_amdgcn_s_setprio(0);

        // exp0 + P0 write (t-local cols 0..31)
        #pragma unroll
        for (int mm = 0; mm < 2; ++mm)
            #pragma unroll
            for (int tt = 0; tt < 2; ++tt) {
                float e0 = EXP2F(s0[tt][mm][0]);
                float e1 = EXP2F(s0[tt][mm][1]);
                float e2 = EXP2F(s0[tt][mm][2]);
                float e3 = EXP2F(s0[tt][mm][3]);
                l_i[mm] += (e0 + e1) + (e2 + e3);
                uint2 pk;
                pk.x = pack_trunc(e0, e1);
                pk.y = pack_trunc(e2, e3);
                *(uint2*)&Pw[(mm * 16 + lr) * 40 + tt * 16 + lq * 4] = pk;
            }

        // ---- QK^T half 1: keys t0+32..t0+63 (overlaps P0 write latency) ----
        f32x4 s1[2][2] = {};
        __builtin_amdgcn_s_setprio(1);
        #pragma unroll
        for (int ks = 0; ks < 2; ++ks)
            #pragma unroll
            for (int tt = 0; tt < 2; ++tt) {
                bf16x8 kf = *(bf16x8*)&Ks[(((tt + 2) * 16 + lr) * 64 + ks * 32 + lq * 8) ^ swz];
                #pragma unroll
                for (int mm = 0; mm < 2; ++mm)
                    s1[tt][mm] = __builtin_amdgcn_mfma_f32_16x16x32_bf16(kf, qf[mm][ks], s1[tt][mm], 0, 0, 0);
            }
        __builtin_amdgcn_s_setprio(0);

        asm volatile("s_waitcnt lgkmcnt(0)" ::: "memory");   // P0 writes done

        // ---- PV half 0: V cols t0..t0+31 (MFMAs overlap exp1 below) ----
        __builtin_amdgcn_s_setprio(1);
        {
            bf16x8 pf[2];
            #pragma unroll
            for (int mm = 0; mm < 2; ++mm)
                pf[mm] = *(bf16x8*)&Pw[(mm * 16 + lr) * 40 + lq * 8];
            #pragma unroll
            for (int j = 0; j < 4; ++j) {
                bf16x8 vf = *(bf16x8*)&Vs[((j * 16 + lr) * 64 + lq * 8) ^ swz];
                #pragma unroll
                for (int mm = 0; mm < 2; ++mm)
                    oacc[mm][j] = __builtin_amdgcn_mfma_f32_16x16x32_bf16(vf, pf[mm], oacc[mm][j], 0, 0, 0);
            }
        }
        __builtin_amdgcn_s_setprio(0);

        // exp1 + P1 write (reuses P slots; WAR-safe: PV(h0) reads issued first)
        #pragma unroll
        for (int mm = 0; mm < 2; ++mm)
            #pragma unroll
            for (int tt = 0; tt < 2; ++tt) {
                float e0 = EXP2F(s1[tt][mm][0]);
                float e1 = EXP2F(s1[tt][mm][1]);
                float e2 = EXP2F(s1[tt][mm][2]);
                float e3 = EXP2F(s1[tt][mm][3]);
                l_i[mm] += (e0 + e1) + (e2 + e3);
                uint2 pk;
                pk.x = pack_trunc(e0, e1);
                pk.y = pack_trunc(e2, e3);
                *(uint2*)&Pw[(mm * 16 + lr) * 40 + tt * 16 + lq * 4] = pk;
            }

        asm volatile("s_waitcnt lgkmcnt(0)" ::: "memory");   // P1 writes done

        // ---- PV half 1: V cols t0+32..t0+63 ----
        __builtin_amdgcn_s_setprio(1);
        {
            bf16x8 pf[2];
            #pragma unroll
            for (int mm = 0; mm < 2; ++mm)
                pf[mm] = *(bf16x8*)&Pw[(mm * 16 + lr) * 40 + lq * 8];
            #pragma unroll
            for (int j = 0; j < 4; ++j) {
                bf16x8 vf = *(bf16x8*)&Vs[((j * 16 + lr) * 64 + 32 + lq * 8) ^ swz];
                #pragma unroll
                for (int mm = 0; mm < 2; ++mm)
                    oacc[mm][j] = __builtin_amdgcn_mfma_f32_16x16x32_bf16(vf, pf[mm], oacc[mm][j], 0, 0, 0);
            }
        }
        __builtin_amdgcn_s_setprio(0);
    }

    float inv[2];
    #pragma unroll
    for (int mm = 0; mm < 2; ++mm) {
        float t = l_i[mm];
        t += __shfl_xor(t, 16);
        t += __shfl_xor(t, 32);
        inv[mm] = 1.0f / t;
    }

    // o store: D row = e_local = lq*4+r (4 consecutive e), col = m = lr.
    #pragma unroll
    for (int mm = 0; mm < 2; ++mm)
        #pragma unroll
        for (int j = 0; j < 4; ++j) {
            f32x4 v = oacc[mm][j];
            v[0] *= inv[mm]; v[1] *= inv[mm]; v[2] *= inv[mm]; v[3] *= inv[mm];
            *(ushort4*)&o[(size_t)(b * SQ_ + q0 + w * 32 + mm * 16 + lr) * HD_ +
                          h * DK_ + j * 16 + lq * 4] = pack4(v);
        }
}

// ---------------------------------------------------------------------------
// Output projection v2: p = o @ Wp^T (bf16 in, f32 out) + fused BN partials.
// 128x64 tiles, K=512, register prefetch, raw-barrier k-loop.
// ---------------------------------------------------------------------------
__global__ __launch_bounds__(256) void gemm_out2(const unsigned short* __restrict__ A,
                                                 const unsigned short* __restrict__ W,
                                                 float* __restrict__ C,
                                                 float* __restrict__ gsum,
                                                 float* __restrict__ gsumsq) {
    __shared__ __align__(16) unsigned short As[128 * 72];
    __shared__ __align__(16) unsigned short Ws[64 * 72];
    const int tid = threadIdx.x;
    const int w = tid >> 6, l = tid & 63, lq = l >> 4, lr = l & 15;
    const int n0 = blockIdx.x * 64, m0 = blockIdx.y * 128;
    const int K = 512;

    const int arow = tid >> 1, aoff = (tid & 1) * 32;
    const int wrow = tid >> 2, woff = (tid & 3) * 16;

    f32x4 acc[2][4] = {};
    uint4 aR[4], wR[2];

    {
        const unsigned short* Ar = A + (size_t)(m0 + arow) * K + aoff;
        #pragma unroll
        for (int c = 0; c < 4; ++c) aR[c] = *(const uint4*)(Ar + c * 8);
        const unsigned short* Wr = W + (size_t)(n0 + wrow) * K + woff;
        #pragma unroll
        for (int c = 0; c < 2; ++c) wR[c] = *(const uint4*)(Wr + c * 8);
    }

    for (int k0 = 0; k0 < K; k0 += 64) {
        BAR();
        #pragma unroll
        for (int c = 0; c < 4; ++c)
            *(uint4*)&As[arow * 72 + aoff + c * 8] = aR[c];
        #pragma unroll
        for (int c = 0; c < 2; ++c)
            *(uint4*)&Ws[wrow * 72 + woff + c * 8] = wR[c];

        if (k0 + 64 < K) {
            const unsigned short* Ar = A + (size_t)(m0 + arow) * K + k0 + 64 + aoff;
            #pragma unroll
            for (int c = 0; c < 4; ++c) aR[c] = *(const uint4*)(Ar + c * 8);
            const unsigned short* Wr = W + (size_t)(n0 + wrow) * K + k0 + 64 + woff;
            #pragma unroll
            for (int c = 0; c < 2; ++c) wR[c] = *(const uint4*)(Wr + c * 8);
        }
        WAIT_LGKM0();
        BAR();

        #pragma unroll
        for (int ks = 0; ks < 2; ++ks) {
            bf16x8 a0 = *(bf16x8*)&As[(w * 32 + lr) * 72 + ks * 32 + lq * 8];
            bf16x8 a1 = *(bf16x8*)&As[(w * 32 + 16 + lr) * 72 + ks * 32 + lq * 8];
            #pragma unroll
            for (int j = 0; j < 4; ++j) {
                bf16x8 bb = *(bf16x8*)&Ws[(j * 16 + lr) * 72 + ks * 32 + lq * 8];
                acc[0][j] = __builtin_amdgcn_mfma_f32_16x16x32_bf16(a0, bb, acc[0][j], 0, 0, 0);
                acc[1][j] = __builtin_amdgcn_mfma_f32_16x16x32_bf16(a1, bb, acc[1][j], 0, 0, 0);
            }
        }
    }

    float cs[4] = {}, cq[4] = {};
    #pragma unroll
    for (int m = 0; m < 2; ++m)
        #pragma unroll
        for (int j = 0; j < 4; ++j)
            #pragma unroll
            for (int r = 0; r < 4; ++r) {
                float v = acc[m][j][r];
                C[(size_t)(m0 + w * 32 + m * 16 + lq * 4 + r) * 256 + n0 + j * 16 + lr] = v;
                cs[j] += v;
                cq[j] += v * v;
            }
    #pragma unroll
    for (int j = 0; j < 4; ++j) {
        cs[j] += __shfl_xor(cs[j], 16); cs[j] += __shfl_xor(cs[j], 32);
        cq[j] += __shfl_xor(cq[j], 16); cq[j] += __shfl_xor(cq[j], 32);
    }
    __syncthreads();
    float* red = (float*)As;
    if (lq == 0) {
        #pragma unroll
        for (int j = 0; j < 4; ++j) {
            red[w * 128 + j * 16 + lr]      = cs[j];
            red[w * 128 + 64 + j * 16 + lr] = cq[j];
        }
    }
    __syncthreads();
    if (tid < 128) {
        int col = tid & 63, stat = tid >> 6;
        float t = red[stat * 64 + col] + red[128 + stat * 64 + col] +
                  red[256 + stat * 64 + col] + red[384 + stat * 64 + col];
        atomicAdd((stat ? gsumsq : gsum) + n0 + col, t);
    }
}

// ---------------------------------------------------------------------------
// Normalize + affine + LeakyReLU
// ---------------------------------------------------------------------------
__global__ __launch_bounds__(256) void bn_norm4(const float* __restrict__ p,
                                                const float* __restrict__ gsum,
                                                const float* __restrict__ gsumsq,
                                                const float* __restrict__ gamma,
                                                const float* __restrict__ beta,
                                                float* __restrict__ out) {
    int i = blockIdx.x * 256 + threadIdx.x;
    int c0 = (i * 4) & 255;
    const float invN = 1.0f / (float)NROWS;
    float4 pv = *(const float4*)(p + (size_t)i * 4);
    float vals[4] = {pv.x, pv.y, pv.z, pv.w};
    float res[4];
    #pragma unroll
    for (int k = 0; k < 4; ++k) {
        int c = c0 + k;
        float mean = gsum[c] * invN;
        float var  = gsumsq[c] * invN - mean * mean;
        float v = (vals[k] - mean) * rsqrtf(var + BN_EPS) * gamma[c] + beta[c];
        res[k] = v >= 0.f ? v : NEG_SLOPE * v;
    }
    float4 ov = {res[0], res[1], res[2], res[3]};
    *(float4*)(out + (size_t)i * 4) = ov;
}

// ---------------------------------------------------------------------------
// kernel_launch
// ---------------------------------------------------------------------------
extern "C" void kernel_launch(void* const* d_in, const int* in_sizes, int n_in,
                              void* d_out, int out_size, void* d_ws, size_t ws_size,
                              hipStream_t stream) {
    const float* x     = (const float*)d_in[0];
    const float* q     = (const float*)d_in[1];
    const float* Wq    = (const float*)d_in[2];
    const float* Wk    = (const float*)d_in[3];
    const float* Wv    = (const float*)d_in[4];
    const float* Wp    = (const float*)d_in[5];
    const float* gamma = (const float*)d_in[6];
    const float* beta  = (const float*)d_in[7];
    float* out = (float*)d_out;

    char* base = (char*)d_ws;
    unsigned short* Wqb  = (unsigned short*)(base + 0);          //  512x256 bf16
    unsigned short* Wkvb = (unsigned short*)(base + 262144);     // 1024x256 bf16
    unsigned short* Wpb  = (unsigned short*)(base + 786432);     //  256x512 bf16
    unsigned short* qh   = (unsigned short*)(base + 1048576);    // 16384x512 bf16
    unsigned short* khb  = (unsigned short*)(base + 17825792);   // 16384x512 bf16
    unsigned short* vTb  = (unsigned short*)(base + 34603008);   // [16,8,64,1024] bf16
    unsigned short* ob   = (unsigned short*)(base + 51380224);   // 16384x512 bf16
    float*          pbuf = (float*)        (base + 68157440);    // 16384x256 f32
    float*          stats= (float*)        (base + 84934656);    // 512 f32

    wcast<<<512, 256, 0, stream>>>(Wq, Wk, Wv, Wp, Wqb, Wkvb, Wpb, stats);

    gemm_qkv9<<<1536, 256, 0, stream>>>(q, x, Wqb, Wkvb, qh, khb, vTb);

    attn_mfma13<<<1024, 256, 0, stream>>>(qh, khb, vTb, ob);

    gemm_out2<<<dim3(4, 128), 256, 0, stream>>>(ob, Wpb, pbuf, stats, stats + 256);

    bn_norm4<<<4096, 256, 0, stream>>>(pbuf, stats, stats + 256, gamma, beta, out);
}

// Round 9
// 222.861 us; speedup vs baseline: 1.1902x; 1.0068x over previous
//
#include <hip/hip_runtime.h>
#include <cstddef>

#define B_    16
#define SQ_   1024
#define SE_   1024
#define CIN_  256
#define DK_   64
#define H_    8
#define HD_   512
#define NROWS 16384
#define BN_EPS 1e-5f
#define NEG_SLOPE 0.01f

typedef __attribute__((ext_vector_type(8))) short bf16x8;
typedef __attribute__((ext_vector_type(4))) float f32x4;

// Raw barrier (no vmcnt drain) + manual LDS-write visibility wait.
#define BAR()        __builtin_amdgcn_s_barrier()
#define WAIT_LGKM0() asm volatile("s_waitcnt lgkmcnt(0)" ::: "memory")

__device__ __forceinline__ unsigned short f2bf(float f) {  // RNE
    unsigned int u = __float_as_uint(f);
    return (unsigned short)((u + 0x7FFFu + ((u >> 16) & 1u)) >> 16);
}

#if __has_builtin(__builtin_amdgcn_perm)
__device__ __forceinline__ unsigned int pack_trunc(float lo, float hi) {
    return __builtin_amdgcn_perm(__float_as_uint(hi), __float_as_uint(lo), 0x07060302u);
}
#else
__device__ __forceinline__ unsigned int pack_trunc(float lo, float hi) {
    return (__float_as_uint(lo) >> 16) | (__float_as_uint(hi) & 0xFFFF0000u);
}
#endif

#if __has_builtin(__builtin_amdgcn_exp2f)
#define EXP2F(x) __builtin_amdgcn_exp2f(x)
#else
#define EXP2F(x) exp2f(x)
#endif

__device__ __forceinline__ ushort4 pack4(f32x4 v) {
    ushort4 p;
    p.x = f2bf(v[0]); p.y = f2bf(v[1]);
    p.z = f2bf(v[2]); p.w = f2bf(v[3]);
    return p;
}

__device__ __forceinline__ bf16x8 cvt8(float4 f0, float4 f1) {  // trunc f32->bf16 x8
    uint4 pk;
    pk.x = pack_trunc(f0.x, f0.y);
    pk.y = pack_trunc(f0.z, f0.w);
    pk.z = pack_trunc(f1.x, f1.y);
    pk.w = pack_trunc(f1.z, f1.w);
    return *(bf16x8*)&pk;
}

// ---------------------------------------------------------------------------
// Weight casts (one dispatch). Wq gets 0.125*log2(e) folded in.
// Blocks 0..1 also zero the BN stats accumulators.
// ---------------------------------------------------------------------------
__global__ __launch_bounds__(256) void wcast(const float* __restrict__ Wq,
                                             const float* __restrict__ Wk,
                                             const float* __restrict__ Wv,
                                             const float* __restrict__ Wp,
                                             unsigned short* __restrict__ dWq,
                                             unsigned short* __restrict__ dWkv,
                                             unsigned short* __restrict__ dWp,
                                             float* __restrict__ stats) {
    if (blockIdx.x < 2) stats[blockIdx.x * 256 + threadIdx.x] = 0.f;
    int i = blockIdx.x * 256 + threadIdx.x;
    int which = i >> 15, off = i & 32767;
    const float* s; unsigned short* d; float sc = 1.0f;
    if (which == 0)      { s = Wq; d = dWq; sc = 0.18033688011112042f; }
    else if (which == 1) { s = Wk; d = dWkv; }
    else if (which == 2) { s = Wv; d = dWkv + 131072; }
    else                 { s = Wp; d = dWp; }
    float4 v = *(const float4*)(s + (size_t)off * 4);
    ushort4 pk;
    pk.x = f2bf(v.x * sc); pk.y = f2bf(v.y * sc);
    pk.z = f2bf(v.z * sc); pk.w = f2bf(v.w * sc);
    *(ushort4*)(d + (size_t)off * 4) = pk;
}

// ---------------------------------------------------------------------------
// Fused Q+KV projection GEMM v9: BARRIER-FREE k-loop.
// W tile (128x256 bf16 = 64 KB) staged in LDS ONCE (XOR-swizzled,
// colu^(row&7) in 16B units); each wave loads its OWN A rows (w*32..+31,
// exclusively owned) directly from global f32, converts in-register,
// double-buffered 2 k-steps deep. Zero barriers in the k-loop.
// XCD-aware decode kept (A panels + W all L2-resident per XCD).
// ---------------------------------------------------------------------------
__global__ __launch_bounds__(256) void gemm_qkv9(const float* __restrict__ qsrc,
                                                 const float* __restrict__ xsrc,
                                                 const unsigned short* __restrict__ Wqb,
                                                 const unsigned short* __restrict__ Wkvb,
                                                 unsigned short* __restrict__ qh,
                                                 unsigned short* __restrict__ khb,
                                                 unsigned short* __restrict__ vTb) {
    __shared__ __align__(16) unsigned short smem[32768];    // 64 KB
    unsigned short* Ws = smem;                              // W tile, swizzled
    unsigned short* Cs = smem;                              // epilogue reuse

    const int tid = threadIdx.x;
    const int w = tid >> 6, l = tid & 63, lq = l >> 4, lr = l & 15;

    // XCD-aware decode (bijective: 1536 = 8 * 192, 192 = 12 * 16)
    const int flat = blockIdx.x;
    const int xcd  = flat & 7;
    const int jj   = flat >> 3;          // 0..191
    const int bx   = jj % 12;
    const int by   = (jj / 12) + xcd * 16;

    const bool isQ = bx < 4;
    const bool isV = bx >= 8;
    const float* A = isQ ? qsrc : xsrc;
    const unsigned short* W = isQ ? Wqb : Wkvb;
    const int n0 = (isQ ? bx : bx - 4) * 128;
    const int m0 = by * 128;

    f32x4 acc[2][8] = {};
    float4 aA[8], aB[8];

    // per-wave A row bases (wave w owns rows w*32 .. w*32+31)
    const float* A0 = A + (size_t)(m0 + w * 32 + lr) * 256 + lq * 8;        // m=0
    const float* A1 = A + (size_t)(m0 + w * 32 + 16 + lr) * 256 + lq * 8;   // m=1

#define LOAD_A(buf, kstep) do {                                              \
        buf[0] = *(const float4*)(A0 + (kstep) * 64);                        \
        buf[1] = *(const float4*)(A0 + (kstep) * 64 + 4);                    \
        buf[2] = *(const float4*)(A0 + (kstep) * 64 + 32);                   \
        buf[3] = *(const float4*)(A0 + (kstep) * 64 + 36);                   \
        buf[4] = *(const float4*)(A1 + (kstep) * 64);                        \
        buf[5] = *(const float4*)(A1 + (kstep) * 64 + 4);                    \
        buf[6] = *(const float4*)(A1 + (kstep) * 64 + 32);                   \
        buf[7] = *(const float4*)(A1 + (kstep) * 64 + 36);                   \
    } while (0)

#define QKV_STEP(buf, kstep) do {                                            \
        _Pragma("unroll")                                                    \
        for (int ks = 0; ks < 2; ++ks) {                                     \
            bf16x8 a0 = cvt8(buf[ks * 2], buf[ks * 2 + 1]);                  \
            bf16x8 a1 = cvt8(buf[4 + ks * 2], buf[4 + ks * 2 + 1]);          \
            const int colu = (kstep) * 8 + ks * 4 + lq;                      \
            const int cswz = colu ^ (lr & 7);                                \
            if (!isV) {                                                      \
                _Pragma("unroll")                                            \
                for (int j = 0; j < 8; ++j) {                                \
                    bf16x8 bb = *(bf16x8*)&Ws[((j * 16 + lr) * 32 + cswz) * 8]; \
                    acc[0][j] = __builtin_amdgcn_mfma_f32_16x16x32_bf16(bb, a0, acc[0][j], 0, 0, 0); \
                    acc[1][j] = __builtin_amdgcn_mfma_f32_16x16x32_bf16(bb, a1, acc[1][j], 0, 0, 0); \
                }                                                            \
            } else {                                                         \
                _Pragma("unroll")                                            \
                for (int j = 0; j < 8; ++j) {                                \
                    bf16x8 bb = *(bf16x8*)&Ws[((j * 16 + lr) * 32 + cswz) * 8]; \
                    acc[0][j] = __builtin_amdgcn_mfma_f32_16x16x32_bf16(a0, bb, acc[0][j], 0, 0, 0); \
                    acc[1][j] = __builtin_amdgcn_mfma_f32_16x16x32_bf16(a1, bb, acc[1][j], 0, 0, 0); \
                }                                                            \
            }                                                                \
        }                                                                    \
    } while (0)

    // step-0 A loads overlap the W staging latency
    LOAD_A(aA, 0);

    // ---- stage W once: 128 rows x 32 16B-units, swizzled colu^(row&7) ----
    #pragma unroll
    for (int i = 0; i < 16; ++i) {
        int u = tid + i * 256;                 // 0..4095
        int row = u >> 5, colu = u & 31;
        uint4 v = *(const uint4*)(W + (size_t)(n0 + row) * 256 + colu * 8);
        *(uint4*)&Ws[(row * 32 + (colu ^ (row & 7))) * 8] = v;
    }
    __syncthreads();   // once per block; no pipelined loads to protect yet

    LOAD_A(aB, 1);
    QKV_STEP(aA, 0);
    LOAD_A(aA, 2);
    QKV_STEP(aB, 1);
    LOAD_A(aB, 3);
    QKV_STEP(aA, 2);
    QKV_STEP(aB, 3);

#undef LOAD_A
#undef QKV_STEP

    // ---- Epilogue: LDS staging, then full-line coalesced stores ----
    __syncthreads();
    const int c16 = tid & 15;
    const int rb  = tid >> 4;
    if (!isV) {
        #pragma unroll
        for (int mf = 0; mf < 2; ++mf)
            #pragma unroll
            for (int j = 0; j < 8; ++j)
                *(ushort4*)&Cs[(w * 32 + mf * 16 + lr) * 144 + j * 16 + lq * 4] =
                    pack4(acc[mf][j]);
        __syncthreads();
        unsigned short* C = isQ ? qh : khb;
        #pragma unroll
        for (int it = 0; it < 8; ++it) {
            int r = it * 16 + rb;
            *(uint4*)(C + (size_t)(m0 + r) * 512 + n0 + c16 * 8) =
                *(const uint4*)(Cs + r * 144 + c16 * 8);
        }
    } else {
        #pragma unroll
        for (int mf = 0; mf < 2; ++mf)
            #pragma unroll
            for (int j = 0; j < 8; ++j)
                *(ushort4*)&Cs[(j * 16 + lr) * 144 + w * 32 + mf * 16 + lq * 4] =
                    pack4(acc[mf][j]);
        __syncthreads();
        const int bb = m0 >> 10, t0 = m0 & 1023;
        #pragma unroll
        for (int it = 0; it < 8; ++it) {
            int el = it * 16 + rb;
            int colv = n0 - 512 + el;
            int hh = colv >> 6, e = colv & 63;
            *(uint4*)(vTb + (size_t)((bb * 8 + hh) * 64 + e) * 1024 + t0 + c16 * 8) =
                *(const uint4*)(Cs + el * 144 + c16 * 8);
        }
    }
}

// ---------------------------------------------------------------------------
// MFMA flash attention v13b: v13 + explicit __launch_bounds__(256, 4).
// R8 post-mortem: with LDS 26.6 KB the allocator targeted 8 waves/EU ->
// 64 VGPRs, spilling ~50 regs of live state to scratch (WRITE_SIZE 176 MB
// vs 16 MB output; dur 67.6->92.5). Declaring 4 waves/EU (= the 4 blocks/CU
// the LDS footprint supports) raises the budget to 128 VGPRs -> no spill,
// keeping the doubled cross-block TLP.
// ---------------------------------------------------------------------------
__global__ __launch_bounds__(256, 4) void attn_mfma13(const unsigned short* __restrict__ qh,
                                                      const unsigned short* __restrict__ kh,
                                                      const unsigned short* __restrict__ vT,
                                                      unsigned short* __restrict__ o) {
    __shared__ __align__(16) unsigned short Ks[64 * 64];      // swizzled  8 KB
    __shared__ __align__(16) unsigned short Vs[64 * 64];      // swizzled  8 KB
    __shared__ __align__(16) unsigned short Ps[4][32 * 40];   // per-wave 10.2 KB

    const int tid = threadIdx.x;
    const int w = tid >> 6, l = tid & 63, lq = l >> 4, lr = l & 15;

    // XCD-aware decode (bijective: 1024 = 8 * 128, 128 = 8 q-chunks * 16 hb)
    const int flat = blockIdx.x;
    const int xcd  = flat & 7;
    const int jj   = flat >> 3;              // 0..127
    const int q0   = (jj & 7) * 128;
    const int hb   = (jj >> 3) + xcd * 16;   // 0..127
    const int h    = hb & 7;
    const int b    = hb >> 3;

    const int swz = (lr & 7) << 3;            // XOR swizzle for K/V reads (shorts)

    // Q fragments: lane lr holds row m = mm*16+lr (mm 0..1)
    bf16x8 qf[2][2];
    #pragma unroll
    for (int mm = 0; mm < 2; ++mm) {
        const unsigned short* qr =
            qh + (size_t)(b * SQ_ + q0 + w * 32 + mm * 16 + lr) * HD_ + h * DK_;
        qf[mm][0] = *(const bf16x8*)(qr + lq * 8);
        qf[mm][1] = *(const bf16x8*)(qr + 32 + lq * 8);
    }

    const unsigned short* kb = kh + (size_t)(b * SE_) * HD_ + h * DK_;
    const unsigned short* vb = vT + (size_t)((b * 8 + h) * 64) * 1024;

    const int se = tid >> 3;                  // 0..31
    const int sc = (tid & 7) * 8;
    const int sswz = (se & 7) << 3;           // staging-write swizzle (rr&7 == se&7)

    float l_i[2] = {};                        // per-lane partial row-sum
    f32x4 oacc[2][4] = {};                    // [mm][e-strip j]; D[e][m]
    unsigned short* Pw = Ps[w];

    // ---- prefetch K/V tile 0 into registers ----
    uint4 kR[2], vR[2];
    #pragma unroll
    for (int ps = 0; ps < 2; ++ps) {
        int rr = se + ps * 32;
        kR[ps] = *(const uint4*)(kb + (size_t)rr * HD_ + sc);
        vR[ps] = *(const uint4*)(vb + (size_t)rr * 1024 + sc);
    }

    for (int t0 = 0; t0 < SE_; t0 += 64) {
        BAR();   // raw: all waves done reading Ks/Vs of prev tile
        #pragma unroll
        for (int ps = 0; ps < 2; ++ps) {
            int rr = se + ps * 32;
            int ad = ((rr * 64 + sc) ^ sswz);
            *(uint4*)&Ks[ad] = kR[ps];
            *(uint4*)&Vs[ad] = vR[ps];
        }
        // issue next tile's loads; they stay in flight across the barrier
        if (t0 + 64 < SE_) {
            #pragma unroll
            for (int ps = 0; ps < 2; ++ps) {
                int rr = se + ps * 32;
                kR[ps] = *(const uint4*)(kb + (size_t)(t0 + 64 + rr) * HD_ + sc);
                vR[ps] = *(const uint4*)(vb + (size_t)rr * 1024 + t0 + 64 + sc);
            }
        }
        WAIT_LGKM0();            // my Ks/Vs writes committed
        BAR();                   // all writes visible; vmcnt NOT drained

        // ---- QK^T half 0: keys t0..t0+31 ----
        f32x4 s0[2][2] = {};
        __builtin_amdgcn_s_setprio(1);
        #pragma unroll
        for (int ks = 0; ks < 2; ++ks)
            #pragma unroll
            for (int tt = 0; tt < 2; ++tt) {
                bf16x8 kf = *(bf16x8*)&Ks[((tt * 16 + lr) * 64 + ks * 32 + lq * 8) ^ swz];
                #pragma unroll
                for (int mm = 0; mm < 2; ++mm)
                    s0[tt][mm] = __builtin_amdgcn_mfma_f32_16x16x32_bf16(kf, qf[mm][ks], s0[tt][mm], 0, 0, 0);
            }
        __builtin_amdgcn_s_setprio(0);

        // exp0 + P0 write (t-local cols 0..31)
        #pragma unroll
        for (int mm = 0; mm < 2; ++mm)
            #pragma unroll
            for (int tt = 0; tt < 2; ++tt) {
                float e0 = EXP2F(s0[tt][mm][0]);
                float e1 = EXP2F(s0[tt][mm][1]);
                float e2 = EXP2F(s0[tt][mm][2]);
                float e3 = EXP2F(s0[tt][mm][3]);
                l_i[mm] += (e0 + e1) + (e2 + e3);
                uint2 pk;
                pk.x = pack_trunc(e0, e1);
                pk.y = pack_trunc(e2, e3);
                *(uint2*)&Pw[(mm * 16 + lr) * 40 + tt * 16 + lq * 4] = pk;
            }

        // ---- QK^T half 1: keys t0+32..t0+63 (overlaps P0 write latency) ----
        f32x4 s1[2][2] = {};
        __builtin_amdgcn_s_setprio(1);
        #pragma unroll
        for (int ks = 0; ks < 2; ++ks)
            #pragma unroll
            for (int tt = 0; tt < 2; ++tt) {
                bf16x8 kf = *(bf16x8*)&Ks[(((tt + 2) * 16 + lr) * 64 + ks * 32 + lq * 8) ^ swz];
                #pragma unroll
                for (int mm = 0; mm < 2; ++mm)
                    s1[tt][mm] = __builtin_amdgcn_mfma_f32_16x16x32_bf16(kf, qf[mm][ks], s1[tt][mm], 0, 0, 0);
            }
        __builtin_amdgcn_s_setprio(0);

        asm volatile("s_waitcnt lgkmcnt(0)" ::: "memory");   // P0 writes done

        // ---- PV half 0: V cols t0..t0+31 (MFMAs overlap exp1 below) ----
        __builtin_amdgcn_s_setprio(1);
        {
            bf16x8 pf[2];
            #pragma unroll
            for (int mm = 0; mm < 2; ++mm)
                pf[mm] = *(bf16x8*)&Pw[(mm * 16 + lr) * 40 + lq * 8];
            #pragma unroll
            for (int j = 0; j < 4; ++j) {
                bf16x8 vf = *(bf16x8*)&Vs[((j * 16 + lr) * 64 + lq * 8) ^ swz];
                #pragma unroll
                for (int mm = 0; mm < 2; ++mm)
                    oacc[mm][j] = __builtin_amdgcn_mfma_f32_16x16x32_bf16(vf, pf[mm], oacc[mm][j], 0, 0, 0);
            }
        }
        __builtin_amdgcn_s_setprio(0);

        // exp1 + P1 write (reuses P slots; WAR-safe: PV(h0) reads issued first)
        #pragma unroll
        for (int mm = 0; mm < 2; ++mm)
            #pragma unroll
            for (int tt = 0; tt < 2; ++tt) {
                float e0 = EXP2F(s1[tt][mm][0]);
                float e1 = EXP2F(s1[tt][mm][1]);
                float e2 = EXP2F(s1[tt][mm][2]);
                float e3 = EXP2F(s1[tt][mm][3]);
                l_i[mm] += (e0 + e1) + (e2 + e3);
                uint2 pk;
                pk.x = pack_trunc(e0, e1);
                pk.y = pack_trunc(e2, e3);
                *(uint2*)&Pw[(mm * 16 + lr) * 40 + tt * 16 + lq * 4] = pk;
            }

        asm volatile("s_waitcnt lgkmcnt(0)" ::: "memory");   // P1 writes done

        // ---- PV half 1: V cols t0+32..t0+63 ----
        __builtin_amdgcn_s_setprio(1);
        {
            bf16x8 pf[2];
            #pragma unroll
            for (int mm = 0; mm < 2; ++mm)
                pf[mm] = *(bf16x8*)&Pw[(mm * 16 + lr) * 40 + lq * 8];
            #pragma unroll
            for (int j = 0; j < 4; ++j) {
                bf16x8 vf = *(bf16x8*)&Vs[((j * 16 + lr) * 64 + 32 + lq * 8) ^ swz];
                #pragma unroll
                for (int mm = 0; mm < 2; ++mm)
                    oacc[mm][j] = __builtin_amdgcn_mfma_f32_16x16x32_bf16(vf, pf[mm], oacc[mm][j], 0, 0, 0);
            }
        }
        __builtin_amdgcn_s_setprio(0);
    }

    float inv[2];
    #pragma unroll
    for (int mm = 0; mm < 2; ++mm) {
        float t = l_i[mm];
        t += __shfl_xor(t, 16);
        t += __shfl_xor(t, 32);
        inv[mm] = 1.0f / t;
    }

    // o store: D row = e_local = lq*4+r (4 consecutive e), col = m = lr.
    #pragma unroll
    for (int mm = 0; mm < 2; ++mm)
        #pragma unroll
        for (int j = 0; j < 4; ++j) {
            f32x4 v = oacc[mm][j];
            v[0] *= inv[mm]; v[1] *= inv[mm]; v[2] *= inv[mm]; v[3] *= inv[mm];
            *(ushort4*)&o[(size_t)(b * SQ_ + q0 + w * 32 + mm * 16 + lr) * HD_ +
                          h * DK_ + j * 16 + lq * 4] = pack4(v);
        }
}

// ---------------------------------------------------------------------------
// Output projection v2: p = o @ Wp^T (bf16 in, f32 out) + fused BN partials.
// 128x64 tiles, K=512, register prefetch, raw-barrier k-loop.
// ---------------------------------------------------------------------------
__global__ __launch_bounds__(256) void gemm_out2(const unsigned short* __restrict__ A,
                                                 const unsigned short* __restrict__ W,
                                                 float* __restrict__ C,
                                                 float* __restrict__ gsum,
                                                 float* __restrict__ gsumsq) {
    __shared__ __align__(16) unsigned short As[128 * 72];
    __shared__ __align__(16) unsigned short Ws[64 * 72];
    const int tid = threadIdx.x;
    const int w = tid >> 6, l = tid & 63, lq = l >> 4, lr = l & 15;
    const int n0 = blockIdx.x * 64, m0 = blockIdx.y * 128;
    const int K = 512;

    const int arow = tid >> 1, aoff = (tid & 1) * 32;
    const int wrow = tid >> 2, woff = (tid & 3) * 16;

    f32x4 acc[2][4] = {};
    uint4 aR[4], wR[2];

    {
        const unsigned short* Ar = A + (size_t)(m0 + arow) * K + aoff;
        #pragma unroll
        for (int c = 0; c < 4; ++c) aR[c] = *(const uint4*)(Ar + c * 8);
        const unsigned short* Wr = W + (size_t)(n0 + wrow) * K + woff;
        #pragma unroll
        for (int c = 0; c < 2; ++c) wR[c] = *(const uint4*)(Wr + c * 8);
    }

    for (int k0 = 0; k0 < K; k0 += 64) {
        BAR();
        #pragma unroll
        for (int c = 0; c < 4; ++c)
            *(uint4*)&As[arow * 72 + aoff + c * 8] = aR[c];
        #pragma unroll
        for (int c = 0; c < 2; ++c)
            *(uint4*)&Ws[wrow * 72 + woff + c * 8] = wR[c];

        if (k0 + 64 < K) {
            const unsigned short* Ar = A + (size_t)(m0 + arow) * K + k0 + 64 + aoff;
            #pragma unroll
            for (int c = 0; c < 4; ++c) aR[c] = *(const uint4*)(Ar + c * 8);
            const unsigned short* Wr = W + (size_t)(n0 + wrow) * K + k0 + 64 + woff;
            #pragma unroll
            for (int c = 0; c < 2; ++c) wR[c] = *(const uint4*)(Wr + c * 8);
        }
        WAIT_LGKM0();
        BAR();

        #pragma unroll
        for (int ks = 0; ks < 2; ++ks) {
            bf16x8 a0 = *(bf16x8*)&As[(w * 32 + lr) * 72 + ks * 32 + lq * 8];
            bf16x8 a1 = *(bf16x8*)&As[(w * 32 + 16 + lr) * 72 + ks * 32 + lq * 8];
            #pragma unroll
            for (int j = 0; j < 4; ++j) {
                bf16x8 bb = *(bf16x8*)&Ws[(j * 16 + lr) * 72 + ks * 32 + lq * 8];
                acc[0][j] = __builtin_amdgcn_mfma_f32_16x16x32_bf16(a0, bb, acc[0][j], 0, 0, 0);
                acc[1][j] = __builtin_amdgcn_mfma_f32_16x16x32_bf16(a1, bb, acc[1][j], 0, 0, 0);
            }
        }
    }

    float cs[4] = {}, cq[4] = {};
    #pragma unroll
    for (int m = 0; m < 2; ++m)
        #pragma unroll
        for (int j = 0; j < 4; ++j)
            #pragma unroll
            for (int r = 0; r < 4; ++r) {
                float v = acc[m][j][r];
                C[(size_t)(m0 + w * 32 + m * 16 + lq * 4 + r) * 256 + n0 + j * 16 + lr] = v;
                cs[j] += v;
                cq[j] += v * v;
            }
    #pragma unroll
    for (int j = 0; j < 4; ++j) {
        cs[j] += __shfl_xor(cs[j], 16); cs[j] += __shfl_xor(cs[j], 32);
        cq[j] += __shfl_xor(cq[j], 16); cq[j] += __shfl_xor(cq[j], 32);
    }
    __syncthreads();
    float* red = (float*)As;
    if (lq == 0) {
        #pragma unroll
        for (int j = 0; j < 4; ++j) {
            red[w * 128 + j * 16 + lr]      = cs[j];
            red[w * 128 + 64 + j * 16 + lr] = cq[j];
        }
    }
    __syncthreads();
    if (tid < 128) {
        int col = tid & 63, stat = tid >> 6;
        float t = red[stat * 64 + col] + red[128 + stat * 64 + col] +
                  red[256 + stat * 64 + col] + red[384 + stat * 64 + col];
        atomicAdd((stat ? gsumsq : gsum) + n0 + col, t);
    }
}

// ---------------------------------------------------------------------------
// Normalize + affine + LeakyReLU
// ---------------------------------------------------------------------------
__global__ __launch_bounds__(256) void bn_norm4(const float* __restrict__ p,
                                                const float* __restrict__ gsum,
                                                const float* __restrict__ gsumsq,
                                                const float* __restrict__ gamma,
                                                const float* __restrict__ beta,
                                                float* __restrict__ out) {
    int i = blockIdx.x * 256 + threadIdx.x;
    int c0 = (i * 4) & 255;
    const float invN = 1.0f / (float)NROWS;
    float4 pv = *(const float4*)(p + (size_t)i * 4);
    float vals[4] = {pv.x, pv.y, pv.z, pv.w};
    float res[4];
    #pragma unroll
    for (int k = 0; k < 4; ++k) {
        int c = c0 + k;
        float mean = gsum[c] * invN;
        float var  = gsumsq[c] * invN - mean * mean;
        float v = (vals[k] - mean) * rsqrtf(var + BN_EPS) * gamma[c] + beta[c];
        res[k] = v >= 0.f ? v : NEG_SLOPE * v;
    }
    float4 ov = {res[0], res[1], res[2], res[3]};
    *(float4*)(out + (size_t)i * 4) = ov;
}

// ---------------------------------------------------------------------------
// kernel_launch
// ---------------------------------------------------------------------------
extern "C" void kernel_launch(void* const* d_in, const int* in_sizes, int n_in,
                              void* d_out, int out_size, void* d_ws, size_t ws_size,
                              hipStream_t stream) {
    const float* x     = (const float*)d_in[0];
    const float* q     = (const float*)d_in[1];
    const float* Wq    = (const float*)d_in[2];
    const float* Wk    = (const float*)d_in[3];
    const float* Wv    = (const float*)d_in[4];
    const float* Wp    = (const float*)d_in[5];
    const float* gamma = (const float*)d_in[6];
    const float* beta  = (const float*)d_in[7];
    float* out = (float*)d_out;

    char* base = (char*)d_ws;
    unsigned short* Wqb  = (unsigned short*)(base + 0);          //  512x256 bf16
    unsigned short* Wkvb = (unsigned short*)(base + 262144);     // 1024x256 bf16
    unsigned short* Wpb  = (unsigned short*)(base + 786432);     //  256x512 bf16
    unsigned short* qh   = (unsigned short*)(base + 1048576);    // 16384x512 bf16
    unsigned short* khb  = (unsigned short*)(base + 17825792);   // 16384x512 bf16
    unsigned short* vTb  = (unsigned short*)(base + 34603008);   // [16,8,64,1024] bf16
    unsigned short* ob   = (unsigned short*)(base + 51380224);   // 16384x512 bf16
    float*          pbuf = (float*)        (base + 68157440);    // 16384x256 f32
    float*          stats= (float*)        (base + 84934656);    // 512 f32

    wcast<<<512, 256, 0, stream>>>(Wq, Wk, Wv, Wp, Wqb, Wkvb, Wpb, stats);

    gemm_qkv9<<<1536, 256, 0, stream>>>(q, x, Wqb, Wkvb, qh, khb, vTb);

    attn_mfma13<<<1024, 256, 0, stream>>>(qh, khb, vTb, ob);

    gemm_out2<<<dim3(4, 128), 256, 0, stream>>>(ob, Wpb, pbuf, stats, stats + 256);

    bn_norm4<<<4096, 256, 0, stream>>>(pbuf, stats, stats + 256, gamma, beta, out);
}

// Round 10
// 211.787 us; speedup vs baseline: 1.2524x; 1.0523x over previous
//
#include <hip/hip_runtime.h>
#include <cstddef>

#define B_    16
#define SQ_   1024
#define SE_   1024
#define CIN_  256
#define DK_   64
#define H_    8
#define HD_   512
#define NROWS 16384
#define BN_EPS 1e-5f
#define NEG_SLOPE 0.01f

typedef __attribute__((ext_vector_type(8))) short bf16x8;
typedef __attribute__((ext_vector_type(4))) float f32x4;

// Raw barrier (no vmcnt drain) + manual LDS-write visibility wait.
#define BAR()        __builtin_amdgcn_s_barrier()
#define WAIT_LGKM0() asm volatile("s_waitcnt lgkmcnt(0)" ::: "memory")

__device__ __forceinline__ unsigned short f2bf(float f) {  // RNE
    unsigned int u = __float_as_uint(f);
    return (unsigned short)((u + 0x7FFFu + ((u >> 16) & 1u)) >> 16);
}

#if __has_builtin(__builtin_amdgcn_perm)
__device__ __forceinline__ unsigned int pack_trunc(float lo, float hi) {
    return __builtin_amdgcn_perm(__float_as_uint(hi), __float_as_uint(lo), 0x07060302u);
}
#else
__device__ __forceinline__ unsigned int pack_trunc(float lo, float hi) {
    return (__float_as_uint(lo) >> 16) | (__float_as_uint(hi) & 0xFFFF0000u);
}
#endif

#if __has_builtin(__builtin_amdgcn_exp2f)
#define EXP2F(x) __builtin_amdgcn_exp2f(x)
#else
#define EXP2F(x) exp2f(x)
#endif

__device__ __forceinline__ ushort4 pack4(f32x4 v) {
    ushort4 p;
    p.x = f2bf(v[0]); p.y = f2bf(v[1]);
    p.z = f2bf(v[2]); p.w = f2bf(v[3]);
    return p;
}

__device__ __forceinline__ bf16x8 cvt8(float4 f0, float4 f1) {  // trunc f32->bf16 x8
    uint4 pk;
    pk.x = pack_trunc(f0.x, f0.y);
    pk.y = pack_trunc(f0.z, f0.w);
    pk.z = pack_trunc(f1.x, f1.y);
    pk.w = pack_trunc(f1.z, f1.w);
    return *(bf16x8*)&pk;
}

// ---------------------------------------------------------------------------
// Weight casts (one dispatch). Wq gets 0.125*log2(e) folded in.
// Blocks 0..1 also zero the BN stats accumulators.
// ---------------------------------------------------------------------------
__global__ __launch_bounds__(256) void wcast(const float* __restrict__ Wq,
                                             const float* __restrict__ Wk,
                                             const float* __restrict__ Wv,
                                             const float* __restrict__ Wp,
                                             unsigned short* __restrict__ dWq,
                                             unsigned short* __restrict__ dWkv,
                                             unsigned short* __restrict__ dWp,
                                             float* __restrict__ stats) {
    if (blockIdx.x < 2) stats[blockIdx.x * 256 + threadIdx.x] = 0.f;
    int i = blockIdx.x * 256 + threadIdx.x;
    int which = i >> 15, off = i & 32767;
    const float* s; unsigned short* d; float sc = 1.0f;
    if (which == 0)      { s = Wq; d = dWq; sc = 0.18033688011112042f; }
    else if (which == 1) { s = Wk; d = dWkv; }
    else if (which == 2) { s = Wv; d = dWkv + 131072; }
    else                 { s = Wp; d = dWp; }
    float4 v = *(const float4*)(s + (size_t)off * 4);
    ushort4 pk;
    pk.x = f2bf(v.x * sc); pk.y = f2bf(v.y * sc);
    pk.z = f2bf(v.z * sc); pk.w = f2bf(v.w * sc);
    *(ushort4*)(d + (size_t)off * 4) = pk;
}

// ---------------------------------------------------------------------------
// Fused Q+KV projection GEMM v9: BARRIER-FREE k-loop.
// W tile (128x256 bf16 = 64 KB) staged in LDS ONCE (XOR-swizzled,
// colu^(row&7) in 16B units); each wave loads its OWN A rows (w*32..+31,
// exclusively owned) directly from global f32, converts in-register,
// double-buffered 2 k-steps deep. Zero barriers in the k-loop.
// XCD-aware decode kept (A panels + W all L2-resident per XCD).
// ---------------------------------------------------------------------------
__global__ __launch_bounds__(256) void gemm_qkv9(const float* __restrict__ qsrc,
                                                 const float* __restrict__ xsrc,
                                                 const unsigned short* __restrict__ Wqb,
                                                 const unsigned short* __restrict__ Wkvb,
                                                 unsigned short* __restrict__ qh,
                                                 unsigned short* __restrict__ khb,
                                                 unsigned short* __restrict__ vTb) {
    __shared__ __align__(16) unsigned short smem[32768];    // 64 KB
    unsigned short* Ws = smem;                              // W tile, swizzled
    unsigned short* Cs = smem;                              // epilogue reuse

    const int tid = threadIdx.x;
    const int w = tid >> 6, l = tid & 63, lq = l >> 4, lr = l & 15;

    // XCD-aware decode (bijective: 1536 = 8 * 192, 192 = 12 * 16)
    const int flat = blockIdx.x;
    const int xcd  = flat & 7;
    const int jj   = flat >> 3;          // 0..191
    const int bx   = jj % 12;
    const int by   = (jj / 12) + xcd * 16;

    const bool isQ = bx < 4;
    const bool isV = bx >= 8;
    const float* A = isQ ? qsrc : xsrc;
    const unsigned short* W = isQ ? Wqb : Wkvb;
    const int n0 = (isQ ? bx : bx - 4) * 128;
    const int m0 = by * 128;

    f32x4 acc[2][8] = {};
    float4 aA[8], aB[8];

    // per-wave A row bases (wave w owns rows w*32 .. w*32+31)
    const float* A0 = A + (size_t)(m0 + w * 32 + lr) * 256 + lq * 8;        // m=0
    const float* A1 = A + (size_t)(m0 + w * 32 + 16 + lr) * 256 + lq * 8;   // m=1

#define LOAD_A(buf, kstep) do {                                              \
        buf[0] = *(const float4*)(A0 + (kstep) * 64);                        \
        buf[1] = *(const float4*)(A0 + (kstep) * 64 + 4);                    \
        buf[2] = *(const float4*)(A0 + (kstep) * 64 + 32);                   \
        buf[3] = *(const float4*)(A0 + (kstep) * 64 + 36);                   \
        buf[4] = *(const float4*)(A1 + (kstep) * 64);                        \
        buf[5] = *(const float4*)(A1 + (kstep) * 64 + 4);                    \
        buf[6] = *(const float4*)(A1 + (kstep) * 64 + 32);                   \
        buf[7] = *(const float4*)(A1 + (kstep) * 64 + 36);                   \
    } while (0)

#define QKV_STEP(buf, kstep) do {                                            \
        _Pragma("unroll")                                                    \
        for (int ks = 0; ks < 2; ++ks) {                                     \
            bf16x8 a0 = cvt8(buf[ks * 2], buf[ks * 2 + 1]);                  \
            bf16x8 a1 = cvt8(buf[4 + ks * 2], buf[4 + ks * 2 + 1]);          \
            const int colu = (kstep) * 8 + ks * 4 + lq;                      \
            const int cswz = colu ^ (lr & 7);                                \
            if (!isV) {                                                      \
                _Pragma("unroll")                                            \
                for (int j = 0; j < 8; ++j) {                                \
                    bf16x8 bb = *(bf16x8*)&Ws[((j * 16 + lr) * 32 + cswz) * 8]; \
                    acc[0][j] = __builtin_amdgcn_mfma_f32_16x16x32_bf16(bb, a0, acc[0][j], 0, 0, 0); \
                    acc[1][j] = __builtin_amdgcn_mfma_f32_16x16x32_bf16(bb, a1, acc[1][j], 0, 0, 0); \
                }                                                            \
            } else {                                                         \
                _Pragma("unroll")                                            \
                for (int j = 0; j < 8; ++j) {                                \
                    bf16x8 bb = *(bf16x8*)&Ws[((j * 16 + lr) * 32 + cswz) * 8]; \
                    acc[0][j] = __builtin_amdgcn_mfma_f32_16x16x32_bf16(a0, bb, acc[0][j], 0, 0, 0); \
                    acc[1][j] = __builtin_amdgcn_mfma_f32_16x16x32_bf16(a1, bb, acc[1][j], 0, 0, 0); \
                }                                                            \
            }                                                                \
        }                                                                    \
    } while (0)

    // step-0 A loads overlap the W staging latency
    LOAD_A(aA, 0);

    // ---- stage W once: 128 rows x 32 16B-units, swizzled colu^(row&7) ----
    #pragma unroll
    for (int i = 0; i < 16; ++i) {
        int u = tid + i * 256;                 // 0..4095
        int row = u >> 5, colu = u & 31;
        uint4 v = *(const uint4*)(W + (size_t)(n0 + row) * 256 + colu * 8);
        *(uint4*)&Ws[(row * 32 + (colu ^ (row & 7))) * 8] = v;
    }
    __syncthreads();   // once per block; no pipelined loads to protect yet

    LOAD_A(aB, 1);
    QKV_STEP(aA, 0);
    LOAD_A(aA, 2);
    QKV_STEP(aB, 1);
    LOAD_A(aB, 3);
    QKV_STEP(aA, 2);
    QKV_STEP(aB, 3);

#undef LOAD_A
#undef QKV_STEP

    // ---- Epilogue: LDS staging, then full-line coalesced stores ----
    __syncthreads();
    const int c16 = tid & 15;
    const int rb  = tid >> 4;
    if (!isV) {
        #pragma unroll
        for (int mf = 0; mf < 2; ++mf)
            #pragma unroll
            for (int j = 0; j < 8; ++j)
                *(ushort4*)&Cs[(w * 32 + mf * 16 + lr) * 144 + j * 16 + lq * 4] =
                    pack4(acc[mf][j]);
        __syncthreads();
        unsigned short* C = isQ ? qh : khb;
        #pragma unroll
        for (int it = 0; it < 8; ++it) {
            int r = it * 16 + rb;
            *(uint4*)(C + (size_t)(m0 + r) * 512 + n0 + c16 * 8) =
                *(const uint4*)(Cs + r * 144 + c16 * 8);
        }
    } else {
        #pragma unroll
        for (int mf = 0; mf < 2; ++mf)
            #pragma unroll
            for (int j = 0; j < 8; ++j)
                *(ushort4*)&Cs[(j * 16 + lr) * 144 + w * 32 + mf * 16 + lq * 4] =
                    pack4(acc[mf][j]);
        __syncthreads();
        const int bb = m0 >> 10, t0 = m0 & 1023;
        #pragma unroll
        for (int it = 0; it < 8; ++it) {
            int el = it * 16 + rb;
            int colv = n0 - 512 + el;
            int hh = colv >> 6, e = colv & 63;
            *(uint4*)(vTb + (size_t)((bb * 8 + hh) * 64 + e) * 1024 + t0 + c16 * 8) =
                *(const uint4*)(Cs + el * 144 + c16 * 8);
        }
    }
}

// ---------------------------------------------------------------------------
// MFMA flash attention v13c: v13 + amdgpu_waves_per_eu(4,4).
// R9 post-mortem: __launch_bounds__(256,4) sets only a MINIMUM waves/EU --
// the allocator still targeted 8 waves/EU (64 VGPR) and spilled ~45 regs
// (WRITE_SIZE 206 MB of scratch vs 16 MB output). Pinning the range to
// exactly 4 waves/EU removes any occupancy incentive below a 128-VGPR
// budget -> live state (~80 regs) stays in registers, keeping 4 blocks/CU.
// ---------------------------------------------------------------------------
__global__ __launch_bounds__(256)
__attribute__((amdgpu_waves_per_eu(4, 4)))
void attn_mfma13(const unsigned short* __restrict__ qh,
                 const unsigned short* __restrict__ kh,
                 const unsigned short* __restrict__ vT,
                 unsigned short* __restrict__ o) {
    __shared__ __align__(16) unsigned short Ks[64 * 64];      // swizzled  8 KB
    __shared__ __align__(16) unsigned short Vs[64 * 64];      // swizzled  8 KB
    __shared__ __align__(16) unsigned short Ps[4][32 * 40];   // per-wave 10.2 KB

    const int tid = threadIdx.x;
    const int w = tid >> 6, l = tid & 63, lq = l >> 4, lr = l & 15;

    // XCD-aware decode (bijective: 1024 = 8 * 128, 128 = 8 q-chunks * 16 hb)
    const int flat = blockIdx.x;
    const int xcd  = flat & 7;
    const int jj   = flat >> 3;              // 0..127
    const int q0   = (jj & 7) * 128;
    const int hb   = (jj >> 3) + xcd * 16;   // 0..127
    const int h    = hb & 7;
    const int b    = hb >> 3;

    const int swz = (lr & 7) << 3;            // XOR swizzle for K/V reads (shorts)

    // Q fragments: lane lr holds row m = mm*16+lr (mm 0..1)
    bf16x8 qf[2][2];
    #pragma unroll
    for (int mm = 0; mm < 2; ++mm) {
        const unsigned short* qr =
            qh + (size_t)(b * SQ_ + q0 + w * 32 + mm * 16 + lr) * HD_ + h * DK_;
        qf[mm][0] = *(const bf16x8*)(qr + lq * 8);
        qf[mm][1] = *(const bf16x8*)(qr + 32 + lq * 8);
    }

    const unsigned short* kb = kh + (size_t)(b * SE_) * HD_ + h * DK_;
    const unsigned short* vb = vT + (size_t)((b * 8 + h) * 64) * 1024;

    const int se = tid >> 3;                  // 0..31
    const int sc = (tid & 7) * 8;
    const int sswz = (se & 7) << 3;           // staging-write swizzle (rr&7 == se&7)

    float l_i[2] = {};                        // per-lane partial row-sum
    f32x4 oacc[2][4] = {};                    // [mm][e-strip j]; D[e][m]
    unsigned short* Pw = Ps[w];

    // ---- prefetch K/V tile 0 into registers ----
    uint4 kR[2], vR[2];
    #pragma unroll
    for (int ps = 0; ps < 2; ++ps) {
        int rr = se + ps * 32;
        kR[ps] = *(const uint4*)(kb + (size_t)rr * HD_ + sc);
        vR[ps] = *(const uint4*)(vb + (size_t)rr * 1024 + sc);
    }

    for (int t0 = 0; t0 < SE_; t0 += 64) {
        BAR();   // raw: all waves done reading Ks/Vs of prev tile
        #pragma unroll
        for (int ps = 0; ps < 2; ++ps) {
            int rr = se + ps * 32;
            int ad = ((rr * 64 + sc) ^ sswz);
            *(uint4*)&Ks[ad] = kR[ps];
            *(uint4*)&Vs[ad] = vR[ps];
        }
        // issue next tile's loads; they stay in flight across the barrier
        if (t0 + 64 < SE_) {
            #pragma unroll
            for (int ps = 0; ps < 2; ++ps) {
                int rr = se + ps * 32;
                kR[ps] = *(const uint4*)(kb + (size_t)(t0 + 64 + rr) * HD_ + sc);
                vR[ps] = *(const uint4*)(vb + (size_t)rr * 1024 + t0 + 64 + sc);
            }
        }
        WAIT_LGKM0();            // my Ks/Vs writes committed
        BAR();                   // all writes visible; vmcnt NOT drained

        // ---- QK^T half 0: keys t0..t0+31 ----
        f32x4 s0[2][2] = {};
        __builtin_amdgcn_s_setprio(1);
        #pragma unroll
        for (int ks = 0; ks < 2; ++ks)
            #pragma unroll
            for (int tt = 0; tt < 2; ++tt) {
                bf16x8 kf = *(bf16x8*)&Ks[((tt * 16 + lr) * 64 + ks * 32 + lq * 8) ^ swz];
                #pragma unroll
                for (int mm = 0; mm < 2; ++mm)
                    s0[tt][mm] = __builtin_amdgcn_mfma_f32_16x16x32_bf16(kf, qf[mm][ks], s0[tt][mm], 0, 0, 0);
            }
        __builtin_amdgcn_s_setprio(0);

        // exp0 + P0 write (t-local cols 0..31)
        #pragma unroll
        for (int mm = 0; mm < 2; ++mm)
            #pragma unroll
            for (int tt = 0; tt < 2; ++tt) {
                float e0 = EXP2F(s0[tt][mm][0]);
                float e1 = EXP2F(s0[tt][mm][1]);
                float e2 = EXP2F(s0[tt][mm][2]);
                float e3 = EXP2F(s0[tt][mm][3]);
                l_i[mm] += (e0 + e1) + (e2 + e3);
                uint2 pk;
                pk.x = pack_trunc(e0, e1);
                pk.y = pack_trunc(e2, e3);
                *(uint2*)&Pw[(mm * 16 + lr) * 40 + tt * 16 + lq * 4] = pk;
            }

        // ---- QK^T half 1: keys t0+32..t0+63 (overlaps P0 write latency) ----
        f32x4 s1[2][2] = {};
        __builtin_amdgcn_s_setprio(1);
        #pragma unroll
        for (int ks = 0; ks < 2; ++ks)
            #pragma unroll
            for (int tt = 0; tt < 2; ++tt) {
                bf16x8 kf = *(bf16x8*)&Ks[(((tt + 2) * 16 + lr) * 64 + ks * 32 + lq * 8) ^ swz];
                #pragma unroll
                for (int mm = 0; mm < 2; ++mm)
                    s1[tt][mm] = __builtin_amdgcn_mfma_f32_16x16x32_bf16(kf, qf[mm][ks], s1[tt][mm], 0, 0, 0);
            }
        __builtin_amdgcn_s_setprio(0);

        asm volatile("s_waitcnt lgkmcnt(0)" ::: "memory");   // P0 writes done

        // ---- PV half 0: V cols t0..t0+31 (MFMAs overlap exp1 below) ----
        __builtin_amdgcn_s_setprio(1);
        {
            bf16x8 pf[2];
            #pragma unroll
            for (int mm = 0; mm < 2; ++mm)
                pf[mm] = *(bf16x8*)&Pw[(mm * 16 + lr) * 40 + lq * 8];
            #pragma unroll
            for (int j = 0; j < 4; ++j) {
                bf16x8 vf = *(bf16x8*)&Vs[((j * 16 + lr) * 64 + lq * 8) ^ swz];
                #pragma unroll
                for (int mm = 0; mm < 2; ++mm)
                    oacc[mm][j] = __builtin_amdgcn_mfma_f32_16x16x32_bf16(vf, pf[mm], oacc[mm][j], 0, 0, 0);
            }
        }
        __builtin_amdgcn_s_setprio(0);

        // exp1 + P1 write (reuses P slots; WAR-safe: PV(h0) reads issued first)
        #pragma unroll
        for (int mm = 0; mm < 2; ++mm)
            #pragma unroll
            for (int tt = 0; tt < 2; ++tt) {
                float e0 = EXP2F(s1[tt][mm][0]);
                float e1 = EXP2F(s1[tt][mm][1]);
                float e2 = EXP2F(s1[tt][mm][2]);
                float e3 = EXP2F(s1[tt][mm][3]);
                l_i[mm] += (e0 + e1) + (e2 + e3);
                uint2 pk;
                pk.x = pack_trunc(e0, e1);
                pk.y = pack_trunc(e2, e3);
                *(uint2*)&Pw[(mm * 16 + lr) * 40 + tt * 16 + lq * 4] = pk;
            }

        asm volatile("s_waitcnt lgkmcnt(0)" ::: "memory");   // P1 writes done

        // ---- PV half 1: V cols t0+32..t0+63 ----
        __builtin_amdgcn_s_setprio(1);
        {
            bf16x8 pf[2];
            #pragma unroll
            for (int mm = 0; mm < 2; ++mm)
                pf[mm] = *(bf16x8*)&Pw[(mm * 16 + lr) * 40 + lq * 8];
            #pragma unroll
            for (int j = 0; j < 4; ++j) {
                bf16x8 vf = *(bf16x8*)&Vs[((j * 16 + lr) * 64 + 32 + lq * 8) ^ swz];
                #pragma unroll
                for (int mm = 0; mm < 2; ++mm)
                    oacc[mm][j] = __builtin_amdgcn_mfma_f32_16x16x32_bf16(vf, pf[mm], oacc[mm][j], 0, 0, 0);
            }
        }
        __builtin_amdgcn_s_setprio(0);
    }

    float inv[2];
    #pragma unroll
    for (int mm = 0; mm < 2; ++mm) {
        float t = l_i[mm];
        t += __shfl_xor(t, 16);
        t += __shfl_xor(t, 32);
        inv[mm] = 1.0f / t;
    }

    // o store: D row = e_local = lq*4+r (4 consecutive e), col = m = lr.
    #pragma unroll
    for (int mm = 0; mm < 2; ++mm)
        #pragma unroll
        for (int j = 0; j < 4; ++j) {
            f32x4 v = oacc[mm][j];
            v[0] *= inv[mm]; v[1] *= inv[mm]; v[2] *= inv[mm]; v[3] *= inv[mm];
            *(ushort4*)&o[(size_t)(b * SQ_ + q0 + w * 32 + mm * 16 + lr) * HD_ +
                          h * DK_ + j * 16 + lq * 4] = pack4(v);
        }
}

// ---------------------------------------------------------------------------
// Output projection v2: p = o @ Wp^T (bf16 in, f32 out) + fused BN partials.
// 128x64 tiles, K=512, register prefetch, raw-barrier k-loop.
// ---------------------------------------------------------------------------
__global__ __launch_bounds__(256) void gemm_out2(const unsigned short* __restrict__ A,
                                                 const unsigned short* __restrict__ W,
                                                 float* __restrict__ C,
                                                 float* __restrict__ gsum,
                                                 float* __restrict__ gsumsq) {
    __shared__ __align__(16) unsigned short As[128 * 72];
    __shared__ __align__(16) unsigned short Ws[64 * 72];
    const int tid = threadIdx.x;
    const int w = tid >> 6, l = tid & 63, lq = l >> 4, lr = l & 15;
    const int n0 = blockIdx.x * 64, m0 = blockIdx.y * 128;
    const int K = 512;

    const int arow = tid >> 1, aoff = (tid & 1) * 32;
    const int wrow = tid >> 2, woff = (tid & 3) * 16;

    f32x4 acc[2][4] = {};
    uint4 aR[4], wR[2];

    {
        const unsigned short* Ar = A + (size_t)(m0 + arow) * K + aoff;
        #pragma unroll
        for (int c = 0; c < 4; ++c) aR[c] = *(const uint4*)(Ar + c * 8);
        const unsigned short* Wr = W + (size_t)(n0 + wrow) * K + woff;
        #pragma unroll
        for (int c = 0; c < 2; ++c) wR[c] = *(const uint4*)(Wr + c * 8);
    }

    for (int k0 = 0; k0 < K; k0 += 64) {
        BAR();
        #pragma unroll
        for (int c = 0; c < 4; ++c)
            *(uint4*)&As[arow * 72 + aoff + c * 8] = aR[c];
        #pragma unroll
        for (int c = 0; c < 2; ++c)
            *(uint4*)&Ws[wrow * 72 + woff + c * 8] = wR[c];

        if (k0 + 64 < K) {
            const unsigned short* Ar = A + (size_t)(m0 + arow) * K + k0 + 64 + aoff;
            #pragma unroll
            for (int c = 0; c < 4; ++c) aR[c] = *(const uint4*)(Ar + c * 8);
            const unsigned short* Wr = W + (size_t)(n0 + wrow) * K + k0 + 64 + woff;
            #pragma unroll
            for (int c = 0; c < 2; ++c) wR[c] = *(const uint4*)(Wr + c * 8);
        }
        WAIT_LGKM0();
        BAR();

        #pragma unroll
        for (int ks = 0; ks < 2; ++ks) {
            bf16x8 a0 = *(bf16x8*)&As[(w * 32 + lr) * 72 + ks * 32 + lq * 8];
            bf16x8 a1 = *(bf16x8*)&As[(w * 32 + 16 + lr) * 72 + ks * 32 + lq * 8];
            #pragma unroll
            for (int j = 0; j < 4; ++j) {
                bf16x8 bb = *(bf16x8*)&Ws[(j * 16 + lr) * 72 + ks * 32 + lq * 8];
                acc[0][j] = __builtin_amdgcn_mfma_f32_16x16x32_bf16(a0, bb, acc[0][j], 0, 0, 0);
                acc[1][j] = __builtin_amdgcn_mfma_f32_16x16x32_bf16(a1, bb, acc[1][j], 0, 0, 0);
            }
        }
    }

    float cs[4] = {}, cq[4] = {};
    #pragma unroll
    for (int m = 0; m < 2; ++m)
        #pragma unroll
        for (int j = 0; j < 4; ++j)
            #pragma unroll
            for (int r = 0; r < 4; ++r) {
                float v = acc[m][j][r];
                C[(size_t)(m0 + w * 32 + m * 16 + lq * 4 + r) * 256 + n0 + j * 16 + lr] = v;
                cs[j] += v;
                cq[j] += v * v;
            }
    #pragma unroll
    for (int j = 0; j < 4; ++j) {
        cs[j] += __shfl_xor(cs[j], 16); cs[j] += __shfl_xor(cs[j], 32);
        cq[j] += __shfl_xor(cq[j], 16); cq[j] += __shfl_xor(cq[j], 32);
    }
    __syncthreads();
    float* red = (float*)As;
    if (lq == 0) {
        #pragma unroll
        for (int j = 0; j < 4; ++j) {
            red[w * 128 + j * 16 + lr]      = cs[j];
            red[w * 128 + 64 + j * 16 + lr] = cq[j];
        }
    }
    __syncthreads();
    if (tid < 128) {
        int col = tid & 63, stat = tid >> 6;
        float t = red[stat * 64 + col] + red[128 + stat * 64 + col] +
                  red[256 + stat * 64 + col] + red[384 + stat * 64 + col];
        atomicAdd((stat ? gsumsq : gsum) + n0 + col, t);
    }
}

// ---------------------------------------------------------------------------
// Normalize + affine + LeakyReLU
// ---------------------------------------------------------------------------
__global__ __launch_bounds__(256) void bn_norm4(const float* __restrict__ p,
                                                const float* __restrict__ gsum,
                                                const float* __restrict__ gsumsq,
                                                const float* __restrict__ gamma,
                                                const float* __restrict__ beta,
                                                float* __restrict__ out) {
    int i = blockIdx.x * 256 + threadIdx.x;
    int c0 = (i * 4) & 255;
    const float invN = 1.0f / (float)NROWS;
    float4 pv = *(const float4*)(p + (size_t)i * 4);
    float vals[4] = {pv.x, pv.y, pv.z, pv.w};
    float res[4];
    #pragma unroll
    for (int k = 0; k < 4; ++k) {
        int c = c0 + k;
        float mean = gsum[c] * invN;
        float var  = gsumsq[c] * invN - mean * mean;
        float v = (vals[k] - mean) * rsqrtf(var + BN_EPS) * gamma[c] + beta[c];
        res[k] = v >= 0.f ? v : NEG_SLOPE * v;
    }
    float4 ov = {res[0], res[1], res[2], res[3]};
    *(float4*)(out + (size_t)i * 4) = ov;
}

// ---------------------------------------------------------------------------
// kernel_launch
// ---------------------------------------------------------------------------
extern "C" void kernel_launch(void* const* d_in, const int* in_sizes, int n_in,
                              void* d_out, int out_size, void* d_ws, size_t ws_size,
                              hipStream_t stream) {
    const float* x     = (const float*)d_in[0];
    const float* q     = (const float*)d_in[1];
    const float* Wq    = (const float*)d_in[2];
    const float* Wk    = (const float*)d_in[3];
    const float* Wv    = (const float*)d_in[4];
    const float* Wp    = (const float*)d_in[5];
    const float* gamma = (const float*)d_in[6];
    const float* beta  = (const float*)d_in[7];
    float* out = (float*)d_out;

    char* base = (char*)d_ws;
    unsigned short* Wqb  = (unsigned short*)(base + 0);          //  512x256 bf16
    unsigned short* Wkvb = (unsigned short*)(base + 262144);     // 1024x256 bf16
    unsigned short* Wpb  = (unsigned short*)(base + 786432);     //  256x512 bf16
    unsigned short* qh   = (unsigned short*)(base + 1048576);    // 16384x512 bf16
    unsigned short* khb  = (unsigned short*)(base + 17825792);   // 16384x512 bf16
    unsigned short* vTb  = (unsigned short*)(base + 34603008);   // [16,8,64,1024] bf16
    unsigned short* ob   = (unsigned short*)(base + 51380224);   // 16384x512 bf16
    float*          pbuf = (float*)        (base + 68157440);    // 16384x256 f32
    float*          stats= (float*)        (base + 84934656);    // 512 f32

    wcast<<<512, 256, 0, stream>>>(Wq, Wk, Wv, Wp, Wqb, Wkvb, Wpb, stats);

    gemm_qkv9<<<1536, 256, 0, stream>>>(q, x, Wqb, Wkvb, qh, khb, vTb);

    attn_mfma13<<<1024, 256, 0, stream>>>(qh, khb, vTb, ob);

    gemm_out2<<<dim3(4, 128), 256, 0, stream>>>(ob, Wpb, pbuf, stats, stats + 256);

    bn_norm4<<<4096, 256, 0, stream>>>(pbuf, stats, stats + 256, gamma, beta, out);
}